// Round 11
// baseline (441.357 us; speedup 1.0000x reference)
//
#include <hip/hip_runtime.h>
#include <hip/hip_bf16.h>

typedef __hip_bfloat16 bf16;
typedef __attribute__((ext_vector_type(8))) short bf16x8;   // 8 bf16 = 4 VGPRs
typedef __attribute__((ext_vector_type(4))) float f32x4;

#define T_SEQ 4096
#define NEMBD 2048
#define QKVD  3072
#define QDIM  2048
#define DKV   1024
#define KDIM  512
#define NH    16
#define DH    128
#define NST   16
#define DTR   64
#define WIN   512
#define NCHUNK 64
#define CLEN   64

__device__ inline float bf2f(bf16 x) { return __bfloat162float(x); }

struct F8 { float v[8]; };

// load 8 contiguous bf16 (16B) and widen to fp32 (bf16 bits << 16)
__device__ inline F8 load_b8(const bf16* p) {
  union { uint4 q; unsigned short s[8]; } u;
  u.q = *reinterpret_cast<const uint4*>(p);
  F8 r;
#pragma unroll
  for (int i = 0; i < 8; i++) r.v[i] = __uint_as_float((unsigned)u.s[i] << 16);
  return r;
}

// load 8 elements [idx, idx+8) from an INPUT array whose real dtype is
// bf16 (f32flag=0) or fp32 (f32flag=1). idx must be a multiple of 4.
__device__ inline F8 load8(const void* base, size_t idx, int f32flag) {
  if (f32flag) {
    const float4* p = reinterpret_cast<const float4*>((const float*)base + idx);
    float4 a = p[0], b = p[1];
    F8 r;
    r.v[0]=a.x; r.v[1]=a.y; r.v[2]=a.z; r.v[3]=a.w;
    r.v[4]=b.x; r.v[5]=b.y; r.v[6]=b.z; r.v[7]=b.w;
    return r;
  }
  return load_b8((const bf16*)base + idx);
}

__device__ inline float load1(const void* base, size_t idx, int f32flag) {
  return f32flag ? ((const float*)base)[idx] : bf2f(((const bf16*)base)[idx]);
}

__device__ inline unsigned short f2b_bits(float f) {
  bf16 h = __float2bfloat16(f);  // RNE
  union { bf16 h; unsigned short u; } c; c.h = h; return c.u;
}

__device__ inline ushort4 pack4(float a, float b, float c, float d) {
  ushort4 r; r.x = f2b_bits(a); r.y = f2b_bits(b); r.z = f2b_bits(c); r.w = f2b_bits(d);
  return r;
}

// async global->LDS, 16B per lane; LDS dest is wave-uniform base + lane*16.
__device__ inline void gld_lds16(const void* g, void* l) {
  __builtin_amdgcn_global_load_lds(
      (const __attribute__((address_space(1))) unsigned int*)g,
      (__attribute__((address_space(3))) unsigned int*)l, 16, 0, 0);
}

// ---------------------------------------------------------------------------
// Input-dtype detection (round-1/2 evidence: fp32; keep the hedge, zero cost).
// ---------------------------------------------------------------------------
__global__ void detect_dtype(const unsigned short* __restrict__ x, int* __restrict__ flag) {
  if (threadIdx.x == 0 && blockIdx.x == 0) {
    int c = 0;
    for (int i = 0; i < 128; i++) {
      float v = __uint_as_float((unsigned)x[i] << 16);
      float a = fabsf(v);
      if (a >= 1e-8f && a <= 1e4f) c++;
    }
    flag[0] = (c >= 120) ? 0 : 1;
  }
}

// ---------------------------------------------------------------------------
// Fused conversion: all 5 inputs -> bf16 in ONE launch (saves 4 graph-node
// dispatch overheads). Region boundaries are compile-time constants.
// ---------------------------------------------------------------------------
#define N8_X   (T_SEQ * NEMBD / 8)              // 1048576
#define N8_WA  (QKVD * NEMBD / 8)               //  786432
#define N8_WO  (NEMBD * QDIM / 8)               //  524288
#define N8_XPW (96 * DKV / 8)                   //   12288
#define N8_DTW (DKV * DTR / 8)                  //    8192
#define N8_TOT (N8_X + N8_WA + N8_WO + N8_XPW + N8_DTW)

__global__ __launch_bounds__(256) void cvt_all(
    const void* __restrict__ x, const void* __restrict__ wa,
    const void* __restrict__ wo, const void* __restrict__ xpw,
    const void* __restrict__ dtw, const int* __restrict__ dflag,
    unsigned short* __restrict__ xo, unsigned short* __restrict__ wao,
    unsigned short* __restrict__ woo, unsigned short* __restrict__ xpwo,
    unsigned short* __restrict__ dtwo)
{
  int i = blockIdx.x * 256 + threadIdx.x;
  if (i >= N8_TOT) return;
  const int f = dflag[0];
  const void* in; unsigned short* out; size_t idx;
  if      (i < N8_X)                        { in = x;   out = xo;   idx = i; }
  else if (i < N8_X + N8_WA)                { in = wa;  out = wao;  idx = i - N8_X; }
  else if (i < N8_X + N8_WA + N8_WO)        { in = wo;  out = woo;  idx = i - (N8_X + N8_WA); }
  else if (i < N8_X + N8_WA + N8_WO + N8_XPW) { in = xpw; out = xpwo; idx = i - (N8_X + N8_WA + N8_WO); }
  else                                      { in = dtw; out = dtwo; idx = i - (N8_X + N8_WA + N8_WO + N8_XPW); }
  F8 v = load8(in, idx * 8, f);
  ushort4* o = (ushort4*)(out + idx * 8);
  o[0] = pack4(v.v[0], v.v[1], v.v[2], v.v[3]);
  o[1] = pack4(v.v[4], v.v[5], v.v[6], v.v[7]);
}

// ---------------------------------------------------------------------------
// gemm_wide (round-2 version, best measured: mode-0 ~82 us, verified).
// BM=256 x BN=128 x BK=64, 512 thr / 8 waves (4M x 2N), per-wave 64x64.
// TWO phases per K-tile, 16 MFMA per phase; full 2-tile prefetch into
// buf[g&1]; checkpoint vmcnt(6); verified 0-conflict swizzle; bijective XCD
// swizzle (grids %8==0).  GEMM interior frozen (rounds 0/2/5 invariant).
// ---------------------------------------------------------------------------
__global__ __launch_bounds__(512, 2) void gemm_wide(
    const unsigned short* __restrict__ A, const unsigned short* __restrict__ B,
    int M, int N, int K, int mode,
    bf16* __restrict__ oq, bf16* __restrict__ ou, float* __restrict__ oc)
{
  __shared__ unsigned short lds[2][384 * 64];   // [buf][(256 A-rows + 128 B-rows) * BK]
  const int tid = threadIdx.x;
  const int wave = tid >> 6, lane = tid & 63;
  const int quad = lane >> 4, l16 = lane & 15;
  const int wm = wave >> 1, wn = wave & 1;      // wave grid 4M x 2N
  const int nbx = N >> 7;                       // BN=128
  const int nwg = gridDim.x;
  const int chunk = nwg >> 3;
  const int swz = (blockIdx.x & 7) * chunk + (blockIdx.x >> 3);
  const int bm = (swz / nbx) * 256, bn = (swz % nbx) * 128;

  // ---- staging lane geometry (inverse-swizzled global source) ----
  const int lrow = lane >> 3;                   // 0..7 rows within an 8-row issue
  const int lslot = (lane & 7) ^ lrow;          // pre-swizzled 16B slot
  const unsigned short* Abase = A + (size_t)(bm + wave * 8 + lrow) * K + lslot * 8;
  const unsigned short* Bbase = B + (size_t)(bn + wave * 8 + lrow) * K + lslot * 8;

  // ---- ds_read geometry (swizzled) ----
  const int x7 = l16 & 7;
  const int s0 = ((0 + quad) ^ x7) * 8;         // kstep 0 slot offset (shorts)
  const int s1 = ((4 + quad) ^ x7) * 8;         // kstep 1
  const int arow0 = (wm * 64 + l16) * 64;       // short offset of A frag row
  const int brow0 = (256 + wn * 64 + l16) * 64; // short offset of B frag row

  f32x4 acc[4][4];
#pragma unroll
  for (int i = 0; i < 4; i++)
#pragma unroll
    for (int j = 0; j < 4; j++) acc[i][j] = f32x4{0.f, 0.f, 0.f, 0.f};

  const int NT = K >> 6;                        // 64-wide K tiles (NT >= 3 here)

  // ---- prologue: tile0 -> buf0 (6 groups), tile1 -> buf1 (6 groups) ----
#pragma unroll
  for (int grp = 0; grp < 4; grp++)
    gld_lds16(Abase + (size_t)grp * 64 * K, &lds[0][(grp * 64 + wave * 8) * 64]);
#pragma unroll
  for (int grp = 0; grp < 2; grp++)
    gld_lds16(Bbase + (size_t)grp * 64 * K, &lds[0][(256 + grp * 64 + wave * 8) * 64]);
#pragma unroll
  for (int grp = 0; grp < 4; grp++)
    gld_lds16(Abase + (size_t)grp * 64 * K + 64, &lds[1][(grp * 64 + wave * 8) * 64]);
#pragma unroll
  for (int grp = 0; grp < 2; grp++)
    gld_lds16(Bbase + (size_t)grp * 64 * K + 64, &lds[1][(256 + grp * 64 + wave * 8) * 64]);
  asm volatile("s_waitcnt vmcnt(6)" ::: "memory");   // tile0 landed; tile1 in flight
  __builtin_amdgcn_sched_barrier(0);
  __builtin_amdgcn_s_barrier();

#define MM(m, n) \
  acc[m][n] = __builtin_amdgcn_mfma_f32_16x16x32_bf16(aF[m][0], bF[n][0], acc[m][n], 0, 0, 0); \
  acc[m][n] = __builtin_amdgcn_mfma_f32_16x16x32_bf16(aF[m][1], bF[n][1], acc[m][n], 0, 0, 0);

  for (int g = 0; g < NT; ++g) {
    const unsigned short* L = lds[g & 1];
    unsigned short* Lw = (unsigned short*)L;     // stage target: same buffer (tile g+2)
    const bool stF = (g + 2) < NT;
    const size_t kF = (size_t)(g + 2) * 64;

    bf16x8 aF[4][2], bF[4][2];

    // ---------------- P1: n-half 0 ----------------
#pragma unroll
    for (int m = 0; m < 4; m++) {
      aF[m][0] = *(const bf16x8*)&L[arow0 + m * 1024 + s0];
      aF[m][1] = *(const bf16x8*)&L[arow0 + m * 1024 + s1];
    }
    bF[0][0] = *(const bf16x8*)&L[brow0 +    0 + s0];
    bF[0][1] = *(const bf16x8*)&L[brow0 +    0 + s1];
    bF[1][0] = *(const bf16x8*)&L[brow0 + 1024 + s0];
    bF[1][1] = *(const bf16x8*)&L[brow0 + 1024 + s1];
    __builtin_amdgcn_s_barrier();                // all waves' A+B(n01) reads done
    if (stF) {                                   // stage A(g+2) into dead A-region
#pragma unroll
      for (int grp = 0; grp < 4; grp++)
        gld_lds16(Abase + (size_t)grp * 64 * K + kF, &Lw[(grp * 64 + wave * 8) * 64]);
    }
    __builtin_amdgcn_s_setprio(1);
    MM(0,0); MM(0,1); MM(1,0); MM(1,1);
    MM(2,0); MM(2,1); MM(3,0); MM(3,1);
    __builtin_amdgcn_s_setprio(0);
    __builtin_amdgcn_s_barrier();

    // ---------------- P2: n-half 1 ----------------
    bF[2][0] = *(const bf16x8*)&L[brow0 + 2048 + s0];
    bF[2][1] = *(const bf16x8*)&L[brow0 + 2048 + s1];
    bF[3][0] = *(const bf16x8*)&L[brow0 + 3072 + s0];
    bF[3][1] = *(const bf16x8*)&L[brow0 + 3072 + s1];
    __builtin_amdgcn_s_barrier();                // all waves' B(n23) reads done
    if (stF) {                                   // stage B(g+2) into dead B-region
#pragma unroll
      for (int grp = 0; grp < 2; grp++)
        gld_lds16(Bbase + (size_t)grp * 64 * K + kF, &Lw[(256 + grp * 64 + wave * 8) * 64]);
    }
    __builtin_amdgcn_s_setprio(1);
    MM(0,2); MM(0,3); MM(1,2); MM(1,3);
    MM(2,2); MM(2,3); MM(3,2); MM(3,3);
    __builtin_amdgcn_s_setprio(0);
    if (stF) { asm volatile("s_waitcnt vmcnt(6)" ::: "memory"); }  // drain tile g+1
    else     { asm volatile("s_waitcnt vmcnt(0)" ::: "memory"); }  // tail
    __builtin_amdgcn_sched_barrier(0);
    __builtin_amdgcn_s_barrier();
  }
#undef MM

  // ---- epilogue ----
#pragma unroll
  for (int m = 0; m < 4; m++)
#pragma unroll
    for (int n = 0; n < 4; n++) {
      int gm0 = bm + wm * 64 + m * 16 + quad * 4;
      int gn  = bn + wn * 64 + n * 16 + l16;
#pragma unroll
      for (int r = 0; r < 4; r++) {
        int gm = gm0 + r;
        float v = acc[m][n][r];
        if (mode == 0) {
          if (gn < QDIM) oq[(size_t)gm * QDIM + gn] = __float2bfloat16(v);
          else           ou[(size_t)gm * DKV + (gn - QDIM)] = __float2bfloat16(v);
        } else {
          oc[(size_t)gm * N + gn] = v;
        }
      }
    }
}

// ---------------------------------------------------------------------------
// xdbl via MFMA — ROUND-9 VERSION RESTORED (round-10's K-split x4 regressed:
// the 1.57M fp32 global atomicAdds in the epilogue + the extra memset node
// cost more than the shortened serial chain saved).
// ---------------------------------------------------------------------------
__global__ __launch_bounds__(256) void xdbl_mfma(
    const bf16* __restrict__ u, const unsigned short* __restrict__ xpw_bf,
    float* __restrict__ xd)
{
  __shared__ unsigned short Us[64 * 32];
  __shared__ unsigned short Ws[96 * 32];
  const int tid = threadIdx.x;
  const int wave = tid >> 6, lane = tid & 63;
  const int quad = lane >> 4, l16 = lane & 15;
  const int t0 = blockIdx.x * 64;
  const unsigned short* ub = (const unsigned short*)u;

  f32x4 acc[6];
#pragma unroll
  for (int j = 0; j < 6; j++) acc[j] = f32x4{0.f, 0.f, 0.f, 0.f};

  const int urow = tid >> 2, ucol = (tid & 3) * 8;
  const int wrow0 = tid >> 2, wcol0 = (tid & 3) * 8;
  const int wrow1 = (256 + tid) >> 2;

  uint4 upre = *(const uint4*)(ub + (size_t)(t0 + urow) * DKV + ucol);
  uint4 wpre0 = *(const uint4*)(xpw_bf + (size_t)wrow0 * DKV + wcol0);
  uint4 wpre1 = (tid < 128) ? *(const uint4*)(xpw_bf + (size_t)wrow1 * DKV + wcol0)
                            : uint4{0, 0, 0, 0};

  for (int k0 = 0; k0 < DKV; k0 += 32) {
    __syncthreads();
    *(uint4*)&Us[urow * 32 + ucol] = upre;
    *(uint4*)&Ws[wrow0 * 32 + wcol0] = wpre0;
    if (tid < 128) *(uint4*)&Ws[wrow1 * 32 + wcol0] = wpre1;
    __syncthreads();

    int kn = (k0 + 32 < DKV) ? (k0 + 32) : k0;
    upre  = *(const uint4*)(ub + (size_t)(t0 + urow) * DKV + kn + ucol);
    wpre0 = *(const uint4*)(xpw_bf + (size_t)wrow0 * DKV + kn + wcol0);
    if (tid < 128) wpre1 = *(const uint4*)(xpw_bf + (size_t)wrow1 * DKV + kn + wcol0);

    bf16x8 a = *(const bf16x8*)&Us[(wave * 16 + l16) * 32 + quad * 8];
#pragma unroll
    for (int j = 0; j < 6; j++) {
      bf16x8 b = *(const bf16x8*)&Ws[(j * 16 + l16) * 32 + quad * 8];
      acc[j] = __builtin_amdgcn_mfma_f32_16x16x32_bf16(a, b, acc[j], 0, 0, 0);
    }
  }

#pragma unroll
  for (int j = 0; j < 6; j++)
#pragma unroll
    for (int r = 0; r < 4; r++) {
      int t = t0 + wave * 16 + quad * 4 + r;
      xd[(size_t)t * 96 + j * 16 + l16] = acc[j][r];
    }
}

// ---------------------------------------------------------------------------
// delta via MFMA (unchanged — verified).
// ---------------------------------------------------------------------------
__global__ __launch_bounds__(256) void delta_mfma(
    const float* __restrict__ xd, const unsigned short* __restrict__ dtw_bf,
    const void* __restrict__ dtb, const int* __restrict__ dflag,
    bf16* __restrict__ delta)
{
  __shared__ unsigned short Xs[64 * 72];
  __shared__ unsigned short Ws[128 * 72];
  const int tid = threadIdx.x;
  const int wave = tid >> 6, lane = tid & 63;
  const int quad = lane >> 4, l16 = lane & 15;
  const int t0 = blockIdx.y * 64, d0 = blockIdx.x * 128;

  for (int e = tid; e < 64 * 8; e += 256) {       // Xs: 64 rows x 64 k (fp32->bf16)
    int row = e >> 3, c8 = (e & 7) * 8;
    const float* p = xd + (size_t)(t0 + row) * 96 + c8;
    float4 a = *(const float4*)p, b = *(const float4*)(p + 4);
    *(ushort4*)&Xs[row * 72 + c8]     = pack4(a.x, a.y, a.z, a.w);
    *(ushort4*)&Xs[row * 72 + c8 + 4] = pack4(b.x, b.y, b.z, b.w);
  }
  for (int e = tid; e < 128 * 8; e += 256) {      // Ws: 128 rows x 64 k
    int row = e >> 3, c8 = (e & 7) * 8;
    *(uint4*)&Ws[row * 72 + c8] = *(const uint4*)(dtw_bf + (size_t)(d0 + row) * DTR + c8);
  }
  __syncthreads();

  bf16x8 a0 = *(const bf16x8*)&Xs[(wave * 16 + l16) * 72 + quad * 8];
  bf16x8 a1 = *(const bf16x8*)&Xs[(wave * 16 + l16) * 72 + 32 + quad * 8];

  f32x4 acc[8];
#pragma unroll
  for (int j = 0; j < 8; j++) {
    bf16x8 b0 = *(const bf16x8*)&Ws[(j * 16 + l16) * 72 + quad * 8];
    bf16x8 b1 = *(const bf16x8*)&Ws[(j * 16 + l16) * 72 + 32 + quad * 8];
    acc[j] = __builtin_amdgcn_mfma_f32_16x16x32_bf16(a0, b0, f32x4{0.f, 0.f, 0.f, 0.f}, 0, 0, 0);
    acc[j] = __builtin_amdgcn_mfma_f32_16x16x32_bf16(a1, b1, acc[j], 0, 0, 0);
  }

  const int f = dflag[0];
#pragma unroll
  for (int j = 0; j < 8; j++) {
    int d = d0 + j * 16 + l16;
    float bias = load1(dtb, d, f);
#pragma unroll
    for (int r = 0; r < 4; r++) {
      int t = t0 + wave * 16 + quad * 4 + r;
      float v = acc[j][r] + bias;
      float sp = fmaxf(v, 0.f) + log1pf(expf(-fabsf(v)));   // stable softplus
      delta[(size_t)t * DKV + d] = __float2bfloat16(sp);
    }
  }
}

// ---------------------------------------------------------------------------
// scan kernels (NCHUNK=64 — measured-best config).
// ---------------------------------------------------------------------------
__global__ __launch_bounds__(256) void scan_pass1(
    const bf16* __restrict__ delta, const bf16* __restrict__ u,
    const float* __restrict__ xd, const void* __restrict__ A_log,
    const int* __restrict__ dflag, float* __restrict__ Pb, float* __restrict__ Hl)
{
  const int gid = blockIdx.x * 256 + threadIdx.x;
  const int c = gid >> 14;
  const int r = gid & 16383;
  const int d = r >> 4, n = r & 15;
  const int f = dflag[0];
  const float A = -expf(load1(A_log, d * NST + n, f));
  float p = 1.f, h = 0.f;
  const int t0 = c * CLEN;
  for (int tt = 0; tt < CLEN; tt++) {
    int t = t0 + tt;
    float dl = bf2f(delta[(size_t)t * DKV + d]);
    float uu = bf2f(u[(size_t)t * DKV + d]);
    float bm = xd[(size_t)t * 96 + DTR + n];
    float a = expf(dl * A);
    h = a * h + dl * bm * uu;
    p *= a;
  }
  Pb[gid] = p;
  Hl[gid] = h;
}

// ---------------------------------------------------------------------------
// scan_combine — wave-parallel (kept from round 10; structurally strictly
// better than the 64-serial-load version: 1 load + 6 shfl_up + 1 store).
// Composition (P,H) <- (P*Pp, P*Hp + H); inclusive -> exclusive shift.
// ---------------------------------------------------------------------------
__global__ __launch_bounds__(256) void scan_combine(
    float* __restrict__ Pb, const float* __restrict__ Hl)
{
  const int idx = blockIdx.x * 4 + (threadIdx.x >> 6);   // 0..16383
  const int c = threadIdx.x & 63;                        // chunk = lane
  const size_t off = (size_t)c * 16384 + idx;
  float P = Pb[off], H = Hl[off];
#pragma unroll
  for (int dstep = 1; dstep < 64; dstep <<= 1) {
    float Pp = __shfl_up(P, dstep);
    float Hp = __shfl_up(H, dstep);
    if (c >= dstep) { H = P * Hp + H; P = P * Pp; }
  }
  float Hprev = __shfl_up(H, 1);                         // inclusive -> exclusive
  Pb[off] = (c == 0) ? 0.f : Hprev;
}

// ---------------------------------------------------------------------------
// scan_pass2 — fuses the V-transpose (verified round 9).
// ---------------------------------------------------------------------------
__global__ __launch_bounds__(256) void scan_pass2(
    const bf16* __restrict__ delta, bf16* __restrict__ u,
    const float* __restrict__ xd, const void* __restrict__ A_log,
    const void* __restrict__ Dp, const int* __restrict__ dflag,
    const float* __restrict__ Hin, unsigned short* __restrict__ vt)
{
  __shared__ unsigned short vtile[16][72];      // 16 d x 64 t (+8 pad)
  const int gid = blockIdx.x * 256 + threadIdx.x;
  const int c = gid >> 14;
  const int r = gid & 16383;
  const int d = r >> 4, n = r & 15;
  const int dblk = ((int)(blockIdx.x & 63)) * 16;   // block-uniform d base
  const bool isV = (dblk >= KDIM);                  // uniform branch
  const int f = dflag[0];
  const float A = -expf(load1(A_log, d * NST + n, f));
  const float dpar = load1(Dp, d, f);
  float h = Hin[gid];
  const int t0 = c * CLEN;
  for (int tt = 0; tt < CLEN; tt++) {
    int t = t0 + tt;
    float dl = bf2f(delta[(size_t)t * DKV + d]);
    float uu = bf2f(u[(size_t)t * DKV + d]);
    float bm = xd[(size_t)t * 96 + DTR + n];
    float cm = xd[(size_t)t * 96 + DTR + NST + n];
    float a = expf(dl * A);
    h = a * h + dl * bm * uu;
    float part = h * cm;
    part += __shfl_xor(part, 1);
    part += __shfl_xor(part, 2);
    part += __shfl_xor(part, 4);
    part += __shfl_xor(part, 8);
    if (n == 0) {
      float outv = part + dpar * uu;
      if (isV) vtile[d & 15][tt] = f2b_bits(outv);
      else     u[(size_t)t * DKV + d] = __float2bfloat16(outv);
    }
  }
  if (isV) {
    __syncthreads();
    const int tid = threadIdx.x;
    const int row = tid >> 4, c4 = (tid & 15) * 4;  // 16 rows x 16 thr x 4 shorts
    ushort4 w;
    w.x = vtile[row][c4];     w.y = vtile[row][c4 + 1];
    w.z = vtile[row][c4 + 2]; w.w = vtile[row][c4 + 3];
    *(ushort4*)&vt[(size_t)(dblk - KDIM + row) * T_SEQ + t0 + c4] = w;
  }
}

// ---------------------------------------------------------------------------
// MFMA flash attention — round-0 structure + T5 setprio (verified round 9).
// ---------------------------------------------------------------------------
__global__ __launch_bounds__(256, 4) void attn_mfma(
    const bf16* __restrict__ q, const bf16* __restrict__ kv,
    const unsigned short* __restrict__ vt, bf16* __restrict__ y)
{
  __shared__ unsigned short Ks[32 * 136];
  __shared__ unsigned short Vts[128 * 40];
  __shared__ unsigned short Ps[4][16 * 40];
  const int tid = threadIdx.x;
  const int wave = tid >> 6, lane = tid & 63;
  const int quad = lane >> 4, l16 = lane & 15;
  const int qt = blockIdx.x, h = blockIdx.y, kvh = h >> 2;
  const int t0 = qt * 64;
  const float scale = 0.088388347648318447f;

  bf16x8 af[4];
#pragma unroll
  for (int s = 0; s < 4; s++)
    af[s] = *(const bf16x8*)(q + (size_t)(t0 + wave * 16 + l16) * QDIM
                             + h * DH + s * 32 + quad * 8);

  const int krow = tid >> 4, kc8 = (tid & 15) * 8;
  const int vrow = tid >> 2, vc8 = (tid & 3) * 8;
  const bf16* kgp = kv + (size_t)kvh * DH;
  const unsigned short* vgp = vt + (size_t)(kvh * DH) * T_SEQ;

  float m_r[4], l_p[4];
  f32x4 O[8];
#pragma unroll
  for (int r = 0; r < 4; r++) { m_r[r] = -1e30f; l_p[r] = 0.f; }
#pragma unroll
  for (int dt = 0; dt < 8; dt++) O[dt] = f32x4{0.f, 0.f, 0.f, 0.f};

  const int kb_start = (t0 > WIN - 1) ? ((t0 - (WIN - 1)) >> 5) : 0;
  const int kb_end = (t0 + 63) >> 5;

  uint4 kp0, kp1, vp0, vp1;
  {
    const int kb = kb_start;
    kp0 = *(const uint4*)(kgp + (size_t)(kb * 32 + krow) * DKV + kc8);
    kp1 = *(const uint4*)(kgp + (size_t)(kb * 32 + 16 + krow) * DKV + kc8);
    vp0 = *(const uint4*)(vgp + (size_t)vrow * T_SEQ + kb * 32 + vc8);
    vp1 = *(const uint4*)(vgp + (size_t)(vrow + 64) * T_SEQ + kb * 32 + vc8);
  }

  for (int kb = kb_start; kb <= kb_end; kb++) {
    __syncthreads();
    *(uint4*)&Ks[krow * 136 + kc8]        = kp0;
    *(uint4*)&Ks[(krow + 16) * 136 + kc8] = kp1;
    *(uint4*)&Vts[vrow * 40 + vc8]        = vp0;
    *(uint4*)&Vts[(vrow + 64) * 40 + vc8] = vp1;
    __syncthreads();

    if (kb < kb_end) {
      const int kn = kb + 1;
      kp0 = *(const uint4*)(kgp + (size_t)(kn * 32 + krow) * DKV + kc8);
      kp1 = *(const uint4*)(kgp + (size_t)(kn * 32 + 16 + krow) * DKV + kc8);
      vp0 = *(const uint4*)(vgp + (size_t)vrow * T_SEQ + kn * 32 + vc8);
      vp1 = *(const uint4*)(vgp + (size_t)(vrow + 64) * T_SEQ + kn * 32 + vc8);
    }

    f32x4 S0 = f32x4{0.f, 0.f, 0.f, 0.f}, S1 = f32x4{0.f, 0.f, 0.f, 0.f};
    __builtin_amdgcn_s_setprio(1);
#pragma unroll
    for (int s = 0; s < 4; s++) {
      bf16x8 b0 = *(const bf16x8*)&Ks[(l16) * 136 + s * 32 + quad * 8];
      bf16x8 b1 = *(const bf16x8*)&Ks[(16 + l16) * 136 + s * 32 + quad * 8];
      S0 = __builtin_amdgcn_mfma_f32_16x16x32_bf16(af[s], b0, S0, 0, 0, 0);
      S1 = __builtin_amdgcn_mfma_f32_16x16x32_bf16(af[s], b1, S1, 0, 0, 0);
    }
    __builtin_amdgcn_s_setprio(0);

    const int ka0 = kb * 32 + l16;
    const int ka1 = ka0 + 16;
    const bool full = (kb * 32 >= t0 + 63 - (WIN - 1)) && (kb * 32 + 31 <= t0);

    float v0r[4], v1r[4];
    bool x0r[4], x1r[4];
    bool ok = true;
#pragma unroll
    for (int r = 0; r < 4; r++) {
      int qa = t0 + wave * 16 + quad * 4 + r;
      float v0 = S0[r] * scale, v1 = S1[r] * scale;
      bool x0 = true, x1 = true;
      if (!full) {
        x0 = (ka0 <= qa) && (ka0 > qa - WIN);
        x1 = (ka1 <= qa) && (ka1 > qa - WIN);
        if (!x0) v0 = -1e30f;
        if (!x1) v1 = -1e30f;
      }
      v0r[r] = v0; v1r[r] = v1; x0r[r] = x0; x1r[r] = x1;
      ok = ok && (fmaxf(v0, v1) <= m_r[r] + 8.f);
    }

    if (!__all((int)ok)) {
#pragma unroll
      for (int r = 0; r < 4; r++) {
        float rm = fmaxf(v0r[r], v1r[r]);
        rm = fmaxf(rm, __shfl_xor(rm, 1));
        rm = fmaxf(rm, __shfl_xor(rm, 2));
        rm = fmaxf(rm, __shfl_xor(rm, 4));
        rm = fmaxf(rm, __shfl_xor(rm, 8));
        float mnew = fmaxf(m_r[r], rm);
        float al = __expf(m_r[r] - mnew);
        m_r[r] = mnew;
        l_p[r] *= al;
#pragma unroll
        for (int dt = 0; dt < 8; dt++) O[dt][r] *= al;
      }
    }

#pragma unroll
    for (int r = 0; r < 4; r++) {
      float p0 = x0r[r] ? __expf(v0r[r] - m_r[r]) : 0.f;
      float p1 = x1r[r] ? __expf(v1r[r] - m_r[r]) : 0.f;
      l_p[r] += p0 + p1;
      Ps[wave][(quad * 4 + r) * 40 + l16]      = f2b_bits(p0);
      Ps[wave][(quad * 4 + r) * 40 + 16 + l16] = f2b_bits(p1);
    }

    bf16x8 pa = *(const bf16x8*)&Ps[wave][l16 * 40 + quad * 8];
    __builtin_amdgcn_s_setprio(1);
#pragma unroll
    for (int dt = 0; dt < 8; dt++) {
      bf16x8 b = *(const bf16x8*)&Vts[(dt * 16 + l16) * 40 + quad * 8];
      O[dt] = __builtin_amdgcn_mfma_f32_16x16x32_bf16(pa, b, O[dt], 0, 0, 0);
    }
    __builtin_amdgcn_s_setprio(0);
  }

  float inv[4];
#pragma unroll
  for (int r = 0; r < 4; r++) {
    float l = l_p[r];
    l += __shfl_xor(l, 1);
    l += __shfl_xor(l, 2);
    l += __shfl_xor(l, 4);
    l += __shfl_xor(l, 8);
    inv[r] = 1.f / l;
  }
#pragma unroll
  for (int dt = 0; dt < 8; dt++)
#pragma unroll
    for (int r = 0; r < 4; r++) {
      int row = t0 + wave * 16 + quad * 4 + r;
      y[(size_t)row * QDIM + h * DH + dt * 16 + l16] = __float2bfloat16(O[dt][r] * inv[r]);
    }
}

// ---------------------------------------------------------------------------
extern "C" void kernel_launch(void* const* d_in, const int* in_sizes, int n_in,
                              void* d_out, int out_size, void* d_ws, size_t ws_size,
                              hipStream_t stream)
{
  const void* x      = d_in[0];
  const void* W_attn = d_in[1];
  const void* A_log  = d_in[2];
  const void* xpw    = d_in[3];
  const void* dtw    = d_in[4];
  const void* dtb    = d_in[5];
  const void* Dp     = d_in[6];
  const void* W_o    = d_in[7];

  // Workspace, TOTAL ~69 MiB:
  char* ws = (char*)d_ws;
  int*   dflag = (int*)ws;   ws += 256;
  bf16*  u     = (bf16*)ws;  ws += (size_t)T_SEQ * DKV * 2;        // 8.4 MB, becomes kv in-place
  float* xd    = (float*)ws; ws += (size_t)T_SEQ * 96 * 4;         // 1.6 MB
  char*  yreg  = ws;                                                // y region (16.78 MB)
  bf16*  delta = (bf16*)ws;  ws += (size_t)T_SEQ * DKV * 2;        // 8.4 MB
  ws += (size_t)64 * DKV * NST * 4;                                 // 4.2 MB (y tail)
  ws += (size_t)64 * DKV * NST * 4;                                 // 4.2 MB (y tail)
  unsigned short* x_bf  = (unsigned short*)ws; ws += (size_t)T_SEQ * NEMBD * 2;  // 16.8 MB; Pb/Hl reuse after gemm0
  unsigned short* wa_bf = (unsigned short*)ws; ws += (size_t)QKVD * NEMBD * 2;   // 12.6 MB
  unsigned short* wo_bf = (unsigned short*)ws; ws += (size_t)NEMBD * QDIM * 2;   //  8.4 MB
  unsigned short* vt    = (unsigned short*)ws; ws += (size_t)KDIM * T_SEQ * 2;   //  4.2 MB
  unsigned short* xpw_bf = (unsigned short*)ws; ws += (size_t)96 * DKV * 2;      //  0.2 MB
  unsigned short* dtw_bf = (unsigned short*)ws; ws += (size_t)DKV * DTR * 2;     //  0.13 MB
  bf16*  y     = (bf16*)yreg;

  // Pb/Hl (NCHUNK=64: 4.2 MB each) live in x_bf's region — x_bf is only read
  // by gemm0, which completes before scan_pass1 launches (stream-ordered).
  float* Pb = (float*)x_bf;
  float* Hl = Pb + (size_t)NCHUNK * DKV * NST;

  bf16*  q_bf = (bf16*)d_out;   // q parks in d_out until gemm2 overwrites it
  float* out  = (float*)d_out;

  detect_dtype<<<1, 64, 0, stream>>>((const unsigned short*)x, dflag);
  cvt_all<<<(N8_TOT + 255) / 256, 256, 0, stream>>>(
      x, W_attn, W_o, xpw, dtw, dflag, x_bf, wa_bf, wo_bf, xpw_bf, dtw_bf);

  // BM=256 x BN=128: mode-0 grid = 16*24 = 384, mode-1 grid = 16*16 = 256
  // (exactly 1 block/CU). Both %8 == 0 (bijective XCD swizzle).
  gemm_wide<<<(T_SEQ / 256) * (QKVD / 128), 512, 0, stream>>>(
      x_bf, wa_bf, T_SEQ, QKVD, NEMBD, 0, q_bf, u, nullptr);
  xdbl_mfma<<<T_SEQ / 64, 256, 0, stream>>>(u, xpw_bf, xd);
  delta_mfma<<<dim3(DKV / 128, T_SEQ / 64), 256, 0, stream>>>(xd, dtw_bf, dtb, dflag, delta);
  scan_pass1<<<NCHUNK * 64, 256, 0, stream>>>(delta, u, xd, A_log, dflag, Pb, Hl);
  scan_combine<<<16384 / 4, 256, 0, stream>>>(Pb, Hl);
  scan_pass2<<<NCHUNK * 64, 256, 0, stream>>>(delta, u, xd, A_log, Dp, dflag, Pb, vt);
  attn_mfma<<<dim3(T_SEQ / 64, NH), 256, 0, stream>>>(q_bf, u, vt, y);
  gemm_wide<<<(T_SEQ / 256) * (QDIM / 128), 512, 0, stream>>>(
      (const unsigned short*)y, wo_bf, T_SEQ, QDIM, QDIM, 1, nullptr, nullptr, out);
}

// Round 12
// 427.060 us; speedup vs baseline: 1.0335x; 1.0335x over previous
//
#include <hip/hip_runtime.h>
#include <hip/hip_bf16.h>

typedef __hip_bfloat16 bf16;
typedef __attribute__((ext_vector_type(8))) short bf16x8;   // 8 bf16 = 4 VGPRs
typedef __attribute__((ext_vector_type(4))) float f32x4;

#define T_SEQ 4096
#define NEMBD 2048
#define QKVD  3072
#define QDIM  2048
#define DKV   1024
#define KDIM  512
#define NH    16
#define DH    128
#define NST   16
#define DTR   64
#define WIN   512
#define NCHUNK 64
#define CLEN   64

__device__ inline float bf2f(bf16 x) { return __bfloat162float(x); }

struct F8 { float v[8]; };

// load 8 contiguous bf16 (16B) and widen to fp32 (bf16 bits << 16)
__device__ inline F8 load_b8(const bf16* p) {
  union { uint4 q; unsigned short s[8]; } u;
  u.q = *reinterpret_cast<const uint4*>(p);
  F8 r;
#pragma unroll
  for (int i = 0; i < 8; i++) r.v[i] = __uint_as_float((unsigned)u.s[i] << 16);
  return r;
}

// load 8 elements [idx, idx+8) from an INPUT array whose real dtype is
// bf16 (f32flag=0) or fp32 (f32flag=1). idx must be a multiple of 4.
__device__ inline F8 load8(const void* base, size_t idx, int f32flag) {
  if (f32flag) {
    const float4* p = reinterpret_cast<const float4*>((const float*)base + idx);
    float4 a = p[0], b = p[1];
    F8 r;
    r.v[0]=a.x; r.v[1]=a.y; r.v[2]=a.z; r.v[3]=a.w;
    r.v[4]=b.x; r.v[5]=b.y; r.v[6]=b.z; r.v[7]=b.w;
    return r;
  }
  return load_b8((const bf16*)base + idx);
}

__device__ inline float load1(const void* base, size_t idx, int f32flag) {
  return f32flag ? ((const float*)base)[idx] : bf2f(((const bf16*)base)[idx]);
}

__device__ inline unsigned short f2b_bits(float f) {
  bf16 h = __float2bfloat16(f);  // RNE
  union { bf16 h; unsigned short u; } c; c.h = h; return c.u;
}

__device__ inline ushort4 pack4(float a, float b, float c, float d) {
  ushort4 r; r.x = f2b_bits(a); r.y = f2b_bits(b); r.z = f2b_bits(c); r.w = f2b_bits(d);
  return r;
}

// async global->LDS, 16B per lane; LDS dest is wave-uniform base + lane*16.
__device__ inline void gld_lds16(const void* g, void* l) {
  __builtin_amdgcn_global_load_lds(
      (const __attribute__((address_space(1))) unsigned int*)g,
      (__attribute__((address_space(3))) unsigned int*)l, 16, 0, 0);
}

// ---------------------------------------------------------------------------
// Input-dtype detection (round-1/2 evidence: fp32; keep the hedge, zero cost).
// ---------------------------------------------------------------------------
__global__ void detect_dtype(const unsigned short* __restrict__ x, int* __restrict__ flag) {
  if (threadIdx.x == 0 && blockIdx.x == 0) {
    int c = 0;
    for (int i = 0; i < 128; i++) {
      float v = __uint_as_float((unsigned)x[i] << 16);
      float a = fabsf(v);
      if (a >= 1e-8f && a <= 1e4f) c++;
    }
    flag[0] = (c >= 120) ? 0 : 1;
  }
}

// ---------------------------------------------------------------------------
// Fused conversion: all 5 inputs -> bf16 in ONE launch (saves 4 graph-node
// dispatch overheads). Region boundaries are compile-time constants.
// ---------------------------------------------------------------------------
#define N8_X   (T_SEQ * NEMBD / 8)              // 1048576
#define N8_WA  (QKVD * NEMBD / 8)               //  786432
#define N8_WO  (NEMBD * QDIM / 8)               //  524288
#define N8_XPW (96 * DKV / 8)                   //   12288
#define N8_DTW (DKV * DTR / 8)                  //    8192
#define N8_TOT (N8_X + N8_WA + N8_WO + N8_XPW + N8_DTW)

__global__ __launch_bounds__(256) void cvt_all(
    const void* __restrict__ x, const void* __restrict__ wa,
    const void* __restrict__ wo, const void* __restrict__ xpw,
    const void* __restrict__ dtw, const int* __restrict__ dflag,
    unsigned short* __restrict__ xo, unsigned short* __restrict__ wao,
    unsigned short* __restrict__ woo, unsigned short* __restrict__ xpwo,
    unsigned short* __restrict__ dtwo)
{
  int i = blockIdx.x * 256 + threadIdx.x;
  if (i >= N8_TOT) return;
  const int f = dflag[0];
  const void* in; unsigned short* out; size_t idx;
  if      (i < N8_X)                        { in = x;   out = xo;   idx = i; }
  else if (i < N8_X + N8_WA)                { in = wa;  out = wao;  idx = i - N8_X; }
  else if (i < N8_X + N8_WA + N8_WO)        { in = wo;  out = woo;  idx = i - (N8_X + N8_WA); }
  else if (i < N8_X + N8_WA + N8_WO + N8_XPW) { in = xpw; out = xpwo; idx = i - (N8_X + N8_WA + N8_WO); }
  else                                      { in = dtw; out = dtwo; idx = i - (N8_X + N8_WA + N8_WO + N8_XPW); }
  F8 v = load8(in, idx * 8, f);
  ushort4* o = (ushort4*)(out + idx * 8);
  o[0] = pack4(v.v[0], v.v[1], v.v[2], v.v[3]);
  o[1] = pack4(v.v[4], v.v[5], v.v[6], v.v[7]);
}

// ---------------------------------------------------------------------------
// gemm_wide (round-2 version, best measured: mode-0 ~82 us, verified).
// BM=256 x BN=128 x BK=64, 512 thr / 8 waves (4M x 2N), per-wave 64x64.
// TWO phases per K-tile, 16 MFMA per phase; full 2-tile prefetch into
// buf[g&1]; checkpoint vmcnt(6); verified 0-conflict swizzle; bijective XCD
// swizzle (grids %8==0).  GEMM interior frozen (rounds 0/2/5 invariant).
// ---------------------------------------------------------------------------
__global__ __launch_bounds__(512, 2) void gemm_wide(
    const unsigned short* __restrict__ A, const unsigned short* __restrict__ B,
    int M, int N, int K, int mode,
    bf16* __restrict__ oq, bf16* __restrict__ ou, float* __restrict__ oc)
{
  __shared__ unsigned short lds[2][384 * 64];   // [buf][(256 A-rows + 128 B-rows) * BK]
  const int tid = threadIdx.x;
  const int wave = tid >> 6, lane = tid & 63;
  const int quad = lane >> 4, l16 = lane & 15;
  const int wm = wave >> 1, wn = wave & 1;      // wave grid 4M x 2N
  const int nbx = N >> 7;                       // BN=128
  const int nwg = gridDim.x;
  const int chunk = nwg >> 3;
  const int swz = (blockIdx.x & 7) * chunk + (blockIdx.x >> 3);
  const int bm = (swz / nbx) * 256, bn = (swz % nbx) * 128;

  // ---- staging lane geometry (inverse-swizzled global source) ----
  const int lrow = lane >> 3;                   // 0..7 rows within an 8-row issue
  const int lslot = (lane & 7) ^ lrow;          // pre-swizzled 16B slot
  const unsigned short* Abase = A + (size_t)(bm + wave * 8 + lrow) * K + lslot * 8;
  const unsigned short* Bbase = B + (size_t)(bn + wave * 8 + lrow) * K + lslot * 8;

  // ---- ds_read geometry (swizzled) ----
  const int x7 = l16 & 7;
  const int s0 = ((0 + quad) ^ x7) * 8;         // kstep 0 slot offset (shorts)
  const int s1 = ((4 + quad) ^ x7) * 8;         // kstep 1
  const int arow0 = (wm * 64 + l16) * 64;       // short offset of A frag row
  const int brow0 = (256 + wn * 64 + l16) * 64; // short offset of B frag row

  f32x4 acc[4][4];
#pragma unroll
  for (int i = 0; i < 4; i++)
#pragma unroll
    for (int j = 0; j < 4; j++) acc[i][j] = f32x4{0.f, 0.f, 0.f, 0.f};

  const int NT = K >> 6;                        // 64-wide K tiles (NT >= 3 here)

  // ---- prologue: tile0 -> buf0 (6 groups), tile1 -> buf1 (6 groups) ----
#pragma unroll
  for (int grp = 0; grp < 4; grp++)
    gld_lds16(Abase + (size_t)grp * 64 * K, &lds[0][(grp * 64 + wave * 8) * 64]);
#pragma unroll
  for (int grp = 0; grp < 2; grp++)
    gld_lds16(Bbase + (size_t)grp * 64 * K, &lds[0][(256 + grp * 64 + wave * 8) * 64]);
#pragma unroll
  for (int grp = 0; grp < 4; grp++)
    gld_lds16(Abase + (size_t)grp * 64 * K + 64, &lds[1][(grp * 64 + wave * 8) * 64]);
#pragma unroll
  for (int grp = 0; grp < 2; grp++)
    gld_lds16(Bbase + (size_t)grp * 64 * K + 64, &lds[1][(256 + grp * 64 + wave * 8) * 64]);
  asm volatile("s_waitcnt vmcnt(6)" ::: "memory");   // tile0 landed; tile1 in flight
  __builtin_amdgcn_sched_barrier(0);
  __builtin_amdgcn_s_barrier();

#define MM(m, n) \
  acc[m][n] = __builtin_amdgcn_mfma_f32_16x16x32_bf16(aF[m][0], bF[n][0], acc[m][n], 0, 0, 0); \
  acc[m][n] = __builtin_amdgcn_mfma_f32_16x16x32_bf16(aF[m][1], bF[n][1], acc[m][n], 0, 0, 0);

  for (int g = 0; g < NT; ++g) {
    const unsigned short* L = lds[g & 1];
    unsigned short* Lw = (unsigned short*)L;     // stage target: same buffer (tile g+2)
    const bool stF = (g + 2) < NT;
    const size_t kF = (size_t)(g + 2) * 64;

    bf16x8 aF[4][2], bF[4][2];

    // ---------------- P1: n-half 0 ----------------
#pragma unroll
    for (int m = 0; m < 4; m++) {
      aF[m][0] = *(const bf16x8*)&L[arow0 + m * 1024 + s0];
      aF[m][1] = *(const bf16x8*)&L[arow0 + m * 1024 + s1];
    }
    bF[0][0] = *(const bf16x8*)&L[brow0 +    0 + s0];
    bF[0][1] = *(const bf16x8*)&L[brow0 +    0 + s1];
    bF[1][0] = *(const bf16x8*)&L[brow0 + 1024 + s0];
    bF[1][1] = *(const bf16x8*)&L[brow0 + 1024 + s1];
    __builtin_amdgcn_s_barrier();                // all waves' A+B(n01) reads done
    if (stF) {                                   // stage A(g+2) into dead A-region
#pragma unroll
      for (int grp = 0; grp < 4; grp++)
        gld_lds16(Abase + (size_t)grp * 64 * K + kF, &Lw[(grp * 64 + wave * 8) * 64]);
    }
    __builtin_amdgcn_s_setprio(1);
    MM(0,0); MM(0,1); MM(1,0); MM(1,1);
    MM(2,0); MM(2,1); MM(3,0); MM(3,1);
    __builtin_amdgcn_s_setprio(0);
    __builtin_amdgcn_s_barrier();

    // ---------------- P2: n-half 1 ----------------
    bF[2][0] = *(const bf16x8*)&L[brow0 + 2048 + s0];
    bF[2][1] = *(const bf16x8*)&L[brow0 + 2048 + s1];
    bF[3][0] = *(const bf16x8*)&L[brow0 + 3072 + s0];
    bF[3][1] = *(const bf16x8*)&L[brow0 + 3072 + s1];
    __builtin_amdgcn_s_barrier();                // all waves' B(n23) reads done
    if (stF) {                                   // stage B(g+2) into dead B-region
#pragma unroll
      for (int grp = 0; grp < 2; grp++)
        gld_lds16(Bbase + (size_t)grp * 64 * K + kF, &Lw[(256 + grp * 64 + wave * 8) * 64]);
    }
    __builtin_amdgcn_s_setprio(1);
    MM(0,2); MM(0,3); MM(1,2); MM(1,3);
    MM(2,2); MM(2,3); MM(3,2); MM(3,3);
    __builtin_amdgcn_s_setprio(0);
    if (stF) { asm volatile("s_waitcnt vmcnt(6)" ::: "memory"); }  // drain tile g+1
    else     { asm volatile("s_waitcnt vmcnt(0)" ::: "memory"); }  // tail
    __builtin_amdgcn_sched_barrier(0);
    __builtin_amdgcn_s_barrier();
  }
#undef MM

  // ---- epilogue ----
#pragma unroll
  for (int m = 0; m < 4; m++)
#pragma unroll
    for (int n = 0; n < 4; n++) {
      int gm0 = bm + wm * 64 + m * 16 + quad * 4;
      int gn  = bn + wn * 64 + n * 16 + l16;
#pragma unroll
      for (int r = 0; r < 4; r++) {
        int gm = gm0 + r;
        float v = acc[m][n][r];
        if (mode == 0) {
          if (gn < QDIM) oq[(size_t)gm * QDIM + gn] = __float2bfloat16(v);
          else           ou[(size_t)gm * DKV + (gn - QDIM)] = __float2bfloat16(v);
        } else {
          oc[(size_t)gm * N + gn] = v;
        }
      }
    }
}

// ---------------------------------------------------------------------------
// xdbl via MFMA (round-9 version — verified).
// ---------------------------------------------------------------------------
__global__ __launch_bounds__(256) void xdbl_mfma(
    const bf16* __restrict__ u, const unsigned short* __restrict__ xpw_bf,
    float* __restrict__ xd)
{
  __shared__ unsigned short Us[64 * 32];
  __shared__ unsigned short Ws[96 * 32];
  const int tid = threadIdx.x;
  const int wave = tid >> 6, lane = tid & 63;
  const int quad = lane >> 4, l16 = lane & 15;
  const int t0 = blockIdx.x * 64;
  const unsigned short* ub = (const unsigned short*)u;

  f32x4 acc[6];
#pragma unroll
  for (int j = 0; j < 6; j++) acc[j] = f32x4{0.f, 0.f, 0.f, 0.f};

  const int urow = tid >> 2, ucol = (tid & 3) * 8;
  const int wrow0 = tid >> 2, wcol0 = (tid & 3) * 8;
  const int wrow1 = (256 + tid) >> 2;

  uint4 upre = *(const uint4*)(ub + (size_t)(t0 + urow) * DKV + ucol);
  uint4 wpre0 = *(const uint4*)(xpw_bf + (size_t)wrow0 * DKV + wcol0);
  uint4 wpre1 = (tid < 128) ? *(const uint4*)(xpw_bf + (size_t)wrow1 * DKV + wcol0)
                            : uint4{0, 0, 0, 0};

  for (int k0 = 0; k0 < DKV; k0 += 32) {
    __syncthreads();
    *(uint4*)&Us[urow * 32 + ucol] = upre;
    *(uint4*)&Ws[wrow0 * 32 + wcol0] = wpre0;
    if (tid < 128) *(uint4*)&Ws[wrow1 * 32 + wcol0] = wpre1;
    __syncthreads();

    int kn = (k0 + 32 < DKV) ? (k0 + 32) : k0;
    upre  = *(const uint4*)(ub + (size_t)(t0 + urow) * DKV + kn + ucol);
    wpre0 = *(const uint4*)(xpw_bf + (size_t)wrow0 * DKV + kn + wcol0);
    if (tid < 128) wpre1 = *(const uint4*)(xpw_bf + (size_t)wrow1 * DKV + kn + wcol0);

    bf16x8 a = *(const bf16x8*)&Us[(wave * 16 + l16) * 32 + quad * 8];
#pragma unroll
    for (int j = 0; j < 6; j++) {
      bf16x8 b = *(const bf16x8*)&Ws[(j * 16 + l16) * 32 + quad * 8];
      acc[j] = __builtin_amdgcn_mfma_f32_16x16x32_bf16(a, b, acc[j], 0, 0, 0);
    }
  }

#pragma unroll
  for (int j = 0; j < 6; j++)
#pragma unroll
    for (int r = 0; r < 4; r++) {
      int t = t0 + wave * 16 + quad * 4 + r;
      xd[(size_t)t * 96 + j * 16 + l16] = acc[j][r];
    }
}

// ---------------------------------------------------------------------------
// delta via MFMA (unchanged — verified).
// ---------------------------------------------------------------------------
__global__ __launch_bounds__(256) void delta_mfma(
    const float* __restrict__ xd, const unsigned short* __restrict__ dtw_bf,
    const void* __restrict__ dtb, const int* __restrict__ dflag,
    bf16* __restrict__ delta)
{
  __shared__ unsigned short Xs[64 * 72];
  __shared__ unsigned short Ws[128 * 72];
  const int tid = threadIdx.x;
  const int wave = tid >> 6, lane = tid & 63;
  const int quad = lane >> 4, l16 = lane & 15;
  const int t0 = blockIdx.y * 64, d0 = blockIdx.x * 128;

  for (int e = tid; e < 64 * 8; e += 256) {       // Xs: 64 rows x 64 k (fp32->bf16)
    int row = e >> 3, c8 = (e & 7) * 8;
    const float* p = xd + (size_t)(t0 + row) * 96 + c8;
    float4 a = *(const float4*)p, b = *(const float4*)(p + 4);
    *(ushort4*)&Xs[row * 72 + c8]     = pack4(a.x, a.y, a.z, a.w);
    *(ushort4*)&Xs[row * 72 + c8 + 4] = pack4(b.x, b.y, b.z, b.w);
  }
  for (int e = tid; e < 128 * 8; e += 256) {      // Ws: 128 rows x 64 k
    int row = e >> 3, c8 = (e & 7) * 8;
    *(uint4*)&Ws[row * 72 + c8] = *(const uint4*)(dtw_bf + (size_t)(d0 + row) * DTR + c8);
  }
  __syncthreads();

  bf16x8 a0 = *(const bf16x8*)&Xs[(wave * 16 + l16) * 72 + quad * 8];
  bf16x8 a1 = *(const bf16x8*)&Xs[(wave * 16 + l16) * 72 + 32 + quad * 8];

  f32x4 acc[8];
#pragma unroll
  for (int j = 0; j < 8; j++) {
    bf16x8 b0 = *(const bf16x8*)&Ws[(j * 16 + l16) * 72 + quad * 8];
    bf16x8 b1 = *(const bf16x8*)&Ws[(j * 16 + l16) * 72 + 32 + quad * 8];
    acc[j] = __builtin_amdgcn_mfma_f32_16x16x32_bf16(a0, b0, f32x4{0.f, 0.f, 0.f, 0.f}, 0, 0, 0);
    acc[j] = __builtin_amdgcn_mfma_f32_16x16x32_bf16(a1, b1, acc[j], 0, 0, 0);
  }

  const int f = dflag[0];
#pragma unroll
  for (int j = 0; j < 8; j++) {
    int d = d0 + j * 16 + l16;
    float bias = load1(dtb, d, f);
#pragma unroll
    for (int r = 0; r < 4; r++) {
      int t = t0 + wave * 16 + quad * 4 + r;
      float v = acc[j][r] + bias;
      float sp = fmaxf(v, 0.f) + log1pf(expf(-fabsf(v)));   // stable softplus
      delta[(size_t)t * DKV + d] = __float2bfloat16(sp);
    }
  }
}

// ---------------------------------------------------------------------------
// scan kernels (NCHUNK=64 — measured-best config).
// ---------------------------------------------------------------------------
__global__ __launch_bounds__(256) void scan_pass1(
    const bf16* __restrict__ delta, const bf16* __restrict__ u,
    const float* __restrict__ xd, const void* __restrict__ A_log,
    const int* __restrict__ dflag, float* __restrict__ Pb, float* __restrict__ Hl)
{
  const int gid = blockIdx.x * 256 + threadIdx.x;
  const int c = gid >> 14;
  const int r = gid & 16383;
  const int d = r >> 4, n = r & 15;
  const int f = dflag[0];
  const float A = -expf(load1(A_log, d * NST + n, f));
  float p = 1.f, h = 0.f;
  const int t0 = c * CLEN;
  for (int tt = 0; tt < CLEN; tt++) {
    int t = t0 + tt;
    float dl = bf2f(delta[(size_t)t * DKV + d]);
    float uu = bf2f(u[(size_t)t * DKV + d]);
    float bm = xd[(size_t)t * 96 + DTR + n];
    float a = expf(dl * A);
    h = a * h + dl * bm * uu;
    p *= a;
  }
  Pb[gid] = p;
  Hl[gid] = h;
}

// ---------------------------------------------------------------------------
// scan_combine — REGISTER-BATCHED serial version.  Round-11 A/B proved the
// wave-parallel variant (lane stride 64KB, uncoalesced: 64 cache lines per
// wave-load, 16x over-fetch) cost +14 us vs round-9's serial loop.  This
// version keeps the COALESCED access (consecutive tid -> consecutive idx)
// but issues all 128 independent loads up-front into statically-indexed
// register arrays (full unroll -> VGPRs, rule 20), so they pipeline under
// one ~900-cyc latency window instead of 64 serial rounds.  The prefix
// recurrence then runs entirely in registers with the SAME FP order as the
// original serial loop -> bit-identical output.
// ---------------------------------------------------------------------------
__global__ __launch_bounds__(256) void scan_combine(
    float* __restrict__ Pb, const float* __restrict__ Hl)
{
  const int idx = blockIdx.x * 256 + threadIdx.x;   // 0..16383, coalesced
  float P[NCHUNK], H[NCHUNK];
#pragma unroll
  for (int c = 0; c < NCHUNK; c++) {
    size_t off = (size_t)c * 16384 + idx;
    P[c] = Pb[off];
    H[c] = Hl[off];
  }
  float run = 0.f;
#pragma unroll
  for (int c = 0; c < NCHUNK; c++) {
    float nrun = P[c] * run + H[c];   // same order as original: p*run + hl
    P[c] = run;                       // P[] reused to hold exclusive prefix
    run = nrun;
  }
#pragma unroll
  for (int c = 0; c < NCHUNK; c++)
    Pb[(size_t)c * 16384 + idx] = P[c];
}

// ---------------------------------------------------------------------------
// scan_pass2 — fuses the V-transpose (verified round 9).
// ---------------------------------------------------------------------------
__global__ __launch_bounds__(256) void scan_pass2(
    const bf16* __restrict__ delta, bf16* __restrict__ u,
    const float* __restrict__ xd, const void* __restrict__ A_log,
    const void* __restrict__ Dp, const int* __restrict__ dflag,
    const float* __restrict__ Hin, unsigned short* __restrict__ vt)
{
  __shared__ unsigned short vtile[16][72];      // 16 d x 64 t (+8 pad)
  const int gid = blockIdx.x * 256 + threadIdx.x;
  const int c = gid >> 14;
  const int r = gid & 16383;
  const int d = r >> 4, n = r & 15;
  const int dblk = ((int)(blockIdx.x & 63)) * 16;   // block-uniform d base
  const bool isV = (dblk >= KDIM);                  // uniform branch
  const int f = dflag[0];
  const float A = -expf(load1(A_log, d * NST + n, f));
  const float dpar = load1(Dp, d, f);
  float h = Hin[gid];
  const int t0 = c * CLEN;
  for (int tt = 0; tt < CLEN; tt++) {
    int t = t0 + tt;
    float dl = bf2f(delta[(size_t)t * DKV + d]);
    float uu = bf2f(u[(size_t)t * DKV + d]);
    float bm = xd[(size_t)t * 96 + DTR + n];
    float cm = xd[(size_t)t * 96 + DTR + NST + n];
    float a = expf(dl * A);
    h = a * h + dl * bm * uu;
    float part = h * cm;
    part += __shfl_xor(part, 1);
    part += __shfl_xor(part, 2);
    part += __shfl_xor(part, 4);
    part += __shfl_xor(part, 8);
    if (n == 0) {
      float outv = part + dpar * uu;
      if (isV) vtile[d & 15][tt] = f2b_bits(outv);
      else     u[(size_t)t * DKV + d] = __float2bfloat16(outv);
    }
  }
  if (isV) {
    __syncthreads();
    const int tid = threadIdx.x;
    const int row = tid >> 4, c4 = (tid & 15) * 4;  // 16 rows x 16 thr x 4 shorts
    ushort4 w;
    w.x = vtile[row][c4];     w.y = vtile[row][c4 + 1];
    w.z = vtile[row][c4 + 2]; w.w = vtile[row][c4 + 3];
    *(ushort4*)&vt[(size_t)(dblk - KDIM + row) * T_SEQ + t0 + c4] = w;
  }
}

// ---------------------------------------------------------------------------
// MFMA flash attention — round-0 structure + T5 setprio (verified round 9).
// ---------------------------------------------------------------------------
__global__ __launch_bounds__(256, 4) void attn_mfma(
    const bf16* __restrict__ q, const bf16* __restrict__ kv,
    const unsigned short* __restrict__ vt, bf16* __restrict__ y)
{
  __shared__ unsigned short Ks[32 * 136];
  __shared__ unsigned short Vts[128 * 40];
  __shared__ unsigned short Ps[4][16 * 40];
  const int tid = threadIdx.x;
  const int wave = tid >> 6, lane = tid & 63;
  const int quad = lane >> 4, l16 = lane & 15;
  const int qt = blockIdx.x, h = blockIdx.y, kvh = h >> 2;
  const int t0 = qt * 64;
  const float scale = 0.088388347648318447f;

  bf16x8 af[4];
#pragma unroll
  for (int s = 0; s < 4; s++)
    af[s] = *(const bf16x8*)(q + (size_t)(t0 + wave * 16 + l16) * QDIM
                             + h * DH + s * 32 + quad * 8);

  const int krow = tid >> 4, kc8 = (tid & 15) * 8;
  const int vrow = tid >> 2, vc8 = (tid & 3) * 8;
  const bf16* kgp = kv + (size_t)kvh * DH;
  const unsigned short* vgp = vt + (size_t)(kvh * DH) * T_SEQ;

  float m_r[4], l_p[4];
  f32x4 O[8];
#pragma unroll
  for (int r = 0; r < 4; r++) { m_r[r] = -1e30f; l_p[r] = 0.f; }
#pragma unroll
  for (int dt = 0; dt < 8; dt++) O[dt] = f32x4{0.f, 0.f, 0.f, 0.f};

  const int kb_start = (t0 > WIN - 1) ? ((t0 - (WIN - 1)) >> 5) : 0;
  const int kb_end = (t0 + 63) >> 5;

  uint4 kp0, kp1, vp0, vp1;
  {
    const int kb = kb_start;
    kp0 = *(const uint4*)(kgp + (size_t)(kb * 32 + krow) * DKV + kc8);
    kp1 = *(const uint4*)(kgp + (size_t)(kb * 32 + 16 + krow) * DKV + kc8);
    vp0 = *(const uint4*)(vgp + (size_t)vrow * T_SEQ + kb * 32 + vc8);
    vp1 = *(const uint4*)(vgp + (size_t)(vrow + 64) * T_SEQ + kb * 32 + vc8);
  }

  for (int kb = kb_start; kb <= kb_end; kb++) {
    __syncthreads();
    *(uint4*)&Ks[krow * 136 + kc8]        = kp0;
    *(uint4*)&Ks[(krow + 16) * 136 + kc8] = kp1;
    *(uint4*)&Vts[vrow * 40 + vc8]        = vp0;
    *(uint4*)&Vts[(vrow + 64) * 40 + vc8] = vp1;
    __syncthreads();

    if (kb < kb_end) {
      const int kn = kb + 1;
      kp0 = *(const uint4*)(kgp + (size_t)(kn * 32 + krow) * DKV + kc8);
      kp1 = *(const uint4*)(kgp + (size_t)(kn * 32 + 16 + krow) * DKV + kc8);
      vp0 = *(const uint4*)(vgp + (size_t)vrow * T_SEQ + kn * 32 + vc8);
      vp1 = *(const uint4*)(vgp + (size_t)(vrow + 64) * T_SEQ + kn * 32 + vc8);
    }

    f32x4 S0 = f32x4{0.f, 0.f, 0.f, 0.f}, S1 = f32x4{0.f, 0.f, 0.f, 0.f};
    __builtin_amdgcn_s_setprio(1);
#pragma unroll
    for (int s = 0; s < 4; s++) {
      bf16x8 b0 = *(const bf16x8*)&Ks[(l16) * 136 + s * 32 + quad * 8];
      bf16x8 b1 = *(const bf16x8*)&Ks[(16 + l16) * 136 + s * 32 + quad * 8];
      S0 = __builtin_amdgcn_mfma_f32_16x16x32_bf16(af[s], b0, S0, 0, 0, 0);
      S1 = __builtin_amdgcn_mfma_f32_16x16x32_bf16(af[s], b1, S1, 0, 0, 0);
    }
    __builtin_amdgcn_s_setprio(0);

    const int ka0 = kb * 32 + l16;
    const int ka1 = ka0 + 16;
    const bool full = (kb * 32 >= t0 + 63 - (WIN - 1)) && (kb * 32 + 31 <= t0);

    float v0r[4], v1r[4];
    bool x0r[4], x1r[4];
    bool ok = true;
#pragma unroll
    for (int r = 0; r < 4; r++) {
      int qa = t0 + wave * 16 + quad * 4 + r;
      float v0 = S0[r] * scale, v1 = S1[r] * scale;
      bool x0 = true, x1 = true;
      if (!full) {
        x0 = (ka0 <= qa) && (ka0 > qa - WIN);
        x1 = (ka1 <= qa) && (ka1 > qa - WIN);
        if (!x0) v0 = -1e30f;
        if (!x1) v1 = -1e30f;
      }
      v0r[r] = v0; v1r[r] = v1; x0r[r] = x0; x1r[r] = x1;
      ok = ok && (fmaxf(v0, v1) <= m_r[r] + 8.f);
    }

    if (!__all((int)ok)) {
#pragma unroll
      for (int r = 0; r < 4; r++) {
        float rm = fmaxf(v0r[r], v1r[r]);
        rm = fmaxf(rm, __shfl_xor(rm, 1));
        rm = fmaxf(rm, __shfl_xor(rm, 2));
        rm = fmaxf(rm, __shfl_xor(rm, 4));
        rm = fmaxf(rm, __shfl_xor(rm, 8));
        float mnew = fmaxf(m_r[r], rm);
        float al = __expf(m_r[r] - mnew);
        m_r[r] = mnew;
        l_p[r] *= al;
#pragma unroll
        for (int dt = 0; dt < 8; dt++) O[dt][r] *= al;
      }
    }

#pragma unroll
    for (int r = 0; r < 4; r++) {
      float p0 = x0r[r] ? __expf(v0r[r] - m_r[r]) : 0.f;
      float p1 = x1r[r] ? __expf(v1r[r] - m_r[r]) : 0.f;
      l_p[r] += p0 + p1;
      Ps[wave][(quad * 4 + r) * 40 + l16]      = f2b_bits(p0);
      Ps[wave][(quad * 4 + r) * 40 + 16 + l16] = f2b_bits(p1);
    }

    bf16x8 pa = *(const bf16x8*)&Ps[wave][l16 * 40 + quad * 8];
    __builtin_amdgcn_s_setprio(1);
#pragma unroll
    for (int dt = 0; dt < 8; dt++) {
      bf16x8 b = *(const bf16x8*)&Vts[(dt * 16 + l16) * 40 + quad * 8];
      O[dt] = __builtin_amdgcn_mfma_f32_16x16x32_bf16(pa, b, O[dt], 0, 0, 0);
    }
    __builtin_amdgcn_s_setprio(0);
  }

  float inv[4];
#pragma unroll
  for (int r = 0; r < 4; r++) {
    float l = l_p[r];
    l += __shfl_xor(l, 1);
    l += __shfl_xor(l, 2);
    l += __shfl_xor(l, 4);
    l += __shfl_xor(l, 8);
    inv[r] = 1.f / l;
  }
#pragma unroll
  for (int dt = 0; dt < 8; dt++)
#pragma unroll
    for (int r = 0; r < 4; r++) {
      int row = t0 + wave * 16 + quad * 4 + r;
      y[(size_t)row * QDIM + h * DH + dt * 16 + l16] = __float2bfloat16(O[dt][r] * inv[r]);
    }
}

// ---------------------------------------------------------------------------
extern "C" void kernel_launch(void* const* d_in, const int* in_sizes, int n_in,
                              void* d_out, int out_size, void* d_ws, size_t ws_size,
                              hipStream_t stream)
{
  const void* x      = d_in[0];
  const void* W_attn = d_in[1];
  const void* A_log  = d_in[2];
  const void* xpw    = d_in[3];
  const void* dtw    = d_in[4];
  const void* dtb    = d_in[5];
  const void* Dp     = d_in[6];
  const void* W_o    = d_in[7];

  // Workspace, TOTAL ~69 MiB:
  char* ws = (char*)d_ws;
  int*   dflag = (int*)ws;   ws += 256;
  bf16*  u     = (bf16*)ws;  ws += (size_t)T_SEQ * DKV * 2;        // 8.4 MB, becomes kv in-place
  float* xd    = (float*)ws; ws += (size_t)T_SEQ * 96 * 4;         // 1.6 MB
  char*  yreg  = ws;                                                // y region (16.78 MB)
  bf16*  delta = (bf16*)ws;  ws += (size_t)T_SEQ * DKV * 2;        // 8.4 MB
  ws += (size_t)64 * DKV * NST * 4;                                 // 4.2 MB (y tail)
  ws += (size_t)64 * DKV * NST * 4;                                 // 4.2 MB (y tail)
  unsigned short* x_bf  = (unsigned short*)ws; ws += (size_t)T_SEQ * NEMBD * 2;  // 16.8 MB; Pb/Hl reuse after gemm0
  unsigned short* wa_bf = (unsigned short*)ws; ws += (size_t)QKVD * NEMBD * 2;   // 12.6 MB
  unsigned short* wo_bf = (unsigned short*)ws; ws += (size_t)NEMBD * QDIM * 2;   //  8.4 MB
  unsigned short* vt    = (unsigned short*)ws; ws += (size_t)KDIM * T_SEQ * 2;   //  4.2 MB
  unsigned short* xpw_bf = (unsigned short*)ws; ws += (size_t)96 * DKV * 2;      //  0.2 MB
  unsigned short* dtw_bf = (unsigned short*)ws; ws += (size_t)DKV * DTR * 2;     //  0.13 MB
  bf16*  y     = (bf16*)yreg;

  // Pb/Hl (NCHUNK=64: 4.2 MB each) live in x_bf's region — x_bf is only read
  // by gemm0, which completes before scan_pass1 launches (stream-ordered).
  float* Pb = (float*)x_bf;
  float* Hl = Pb + (size_t)NCHUNK * DKV * NST;

  bf16*  q_bf = (bf16*)d_out;   // q parks in d_out until gemm2 overwrites it
  float* out  = (float*)d_out;

  detect_dtype<<<1, 64, 0, stream>>>((const unsigned short*)x, dflag);
  cvt_all<<<(N8_TOT + 255) / 256, 256, 0, stream>>>(
      x, W_attn, W_o, xpw, dtw, dflag, x_bf, wa_bf, wo_bf, xpw_bf, dtw_bf);

  // BM=256 x BN=128: mode-0 grid = 16*24 = 384, mode-1 grid = 16*16 = 256
  // (exactly 1 block/CU). Both %8 == 0 (bijective XCD swizzle).
  gemm_wide<<<(T_SEQ / 256) * (QKVD / 128), 512, 0, stream>>>(
      x_bf, wa_bf, T_SEQ, QKVD, NEMBD, 0, q_bf, u, nullptr);
  xdbl_mfma<<<T_SEQ / 64, 256, 0, stream>>>(u, xpw_bf, xd);
  delta_mfma<<<dim3(DKV / 128, T_SEQ / 64), 256, 0, stream>>>(xd, dtw_bf, dtb, dflag, delta);
  scan_pass1<<<NCHUNK * 64, 256, 0, stream>>>(delta, u, xd, A_log, dflag, Pb, Hl);
  scan_combine<<<64, 256, 0, stream>>>(Pb, Hl);
  scan_pass2<<<NCHUNK * 64, 256, 0, stream>>>(delta, u, xd, A_log, Dp, dflag, Pb, vt);
  attn_mfma<<<dim3(T_SEQ / 64, NH), 256, 0, stream>>>(q_bf, u, vt, y);
  gemm_wide<<<(T_SEQ / 256) * (QDIM / 128), 512, 0, stream>>>(
      (const unsigned short*)y, wo_bf, T_SEQ, QDIM, QDIM, 1, nullptr, nullptr, out);
}

// Round 13
// 419.764 us; speedup vs baseline: 1.0514x; 1.0174x over previous
//
#include <hip/hip_runtime.h>
#include <hip/hip_bf16.h>

typedef __hip_bfloat16 bf16;
typedef __attribute__((ext_vector_type(8))) short bf16x8;   // 8 bf16 = 4 VGPRs
typedef __attribute__((ext_vector_type(4))) float f32x4;

#define T_SEQ 4096
#define NEMBD 2048
#define QKVD  3072
#define QDIM  2048
#define DKV   1024
#define KDIM  512
#define NH    16
#define DH    128
#define NST   16
#define DTR   64
#define WIN   512
#define NCHUNK 64
#define CLEN   64
#define KSPLIT 4

__device__ inline float bf2f(bf16 x) { return __bfloat162float(x); }

struct F8 { float v[8]; };

// load 8 contiguous bf16 (16B) and widen to fp32 (bf16 bits << 16)
__device__ inline F8 load_b8(const bf16* p) {
  union { uint4 q; unsigned short s[8]; } u;
  u.q = *reinterpret_cast<const uint4*>(p);
  F8 r;
#pragma unroll
  for (int i = 0; i < 8; i++) r.v[i] = __uint_as_float((unsigned)u.s[i] << 16);
  return r;
}

// load 8 elements [idx, idx+8) from an INPUT array whose real dtype is
// bf16 (f32flag=0) or fp32 (f32flag=1). idx must be a multiple of 4.
__device__ inline F8 load8(const void* base, size_t idx, int f32flag) {
  if (f32flag) {
    const float4* p = reinterpret_cast<const float4*>((const float*)base + idx);
    float4 a = p[0], b = p[1];
    F8 r;
    r.v[0]=a.x; r.v[1]=a.y; r.v[2]=a.z; r.v[3]=a.w;
    r.v[4]=b.x; r.v[5]=b.y; r.v[6]=b.z; r.v[7]=b.w;
    return r;
  }
  return load_b8((const bf16*)base + idx);
}

__device__ inline float load1(const void* base, size_t idx, int f32flag) {
  return f32flag ? ((const float*)base)[idx] : bf2f(((const bf16*)base)[idx]);
}

__device__ inline unsigned short f2b_bits(float f) {
  bf16 h = __float2bfloat16(f);  // RNE
  union { bf16 h; unsigned short u; } c; c.h = h; return c.u;
}

__device__ inline ushort4 pack4(float a, float b, float c, float d) {
  ushort4 r; r.x = f2b_bits(a); r.y = f2b_bits(b); r.z = f2b_bits(c); r.w = f2b_bits(d);
  return r;
}

// async global->LDS, 16B per lane; LDS dest is wave-uniform base + lane*16.
__device__ inline void gld_lds16(const void* g, void* l) {
  __builtin_amdgcn_global_load_lds(
      (const __attribute__((address_space(1))) unsigned int*)g,
      (__attribute__((address_space(3))) unsigned int*)l, 16, 0, 0);
}

// ---------------------------------------------------------------------------
// Input-dtype detection (round-1/2 evidence: fp32; keep the hedge, zero cost).
// ---------------------------------------------------------------------------
__global__ void detect_dtype(const unsigned short* __restrict__ x, int* __restrict__ flag) {
  if (threadIdx.x == 0 && blockIdx.x == 0) {
    int c = 0;
    for (int i = 0; i < 128; i++) {
      float v = __uint_as_float((unsigned)x[i] << 16);
      float a = fabsf(v);
      if (a >= 1e-8f && a <= 1e4f) c++;
    }
    flag[0] = (c >= 120) ? 0 : 1;
  }
}

// ---------------------------------------------------------------------------
// Fused conversion: all 5 inputs -> bf16 in ONE launch (saves 4 graph-node
// dispatch overheads). Region boundaries are compile-time constants.
// ---------------------------------------------------------------------------
#define N8_X   (T_SEQ * NEMBD / 8)              // 1048576
#define N8_WA  (QKVD * NEMBD / 8)               //  786432
#define N8_WO  (NEMBD * QDIM / 8)               //  524288
#define N8_XPW (96 * DKV / 8)                   //   12288
#define N8_DTW (DKV * DTR / 8)                  //    8192
#define N8_TOT (N8_X + N8_WA + N8_WO + N8_XPW + N8_DTW)

__global__ __launch_bounds__(256) void cvt_all(
    const void* __restrict__ x, const void* __restrict__ wa,
    const void* __restrict__ wo, const void* __restrict__ xpw,
    const void* __restrict__ dtw, const int* __restrict__ dflag,
    unsigned short* __restrict__ xo, unsigned short* __restrict__ wao,
    unsigned short* __restrict__ woo, unsigned short* __restrict__ xpwo,
    unsigned short* __restrict__ dtwo)
{
  int i = blockIdx.x * 256 + threadIdx.x;
  if (i >= N8_TOT) return;
  const int f = dflag[0];
  const void* in; unsigned short* out; size_t idx;
  if      (i < N8_X)                        { in = x;   out = xo;   idx = i; }
  else if (i < N8_X + N8_WA)                { in = wa;  out = wao;  idx = i - N8_X; }
  else if (i < N8_X + N8_WA + N8_WO)        { in = wo;  out = woo;  idx = i - (N8_X + N8_WA); }
  else if (i < N8_X + N8_WA + N8_WO + N8_XPW) { in = xpw; out = xpwo; idx = i - (N8_X + N8_WA + N8_WO); }
  else                                      { in = dtw; out = dtwo; idx = i - (N8_X + N8_WA + N8_WO + N8_XPW); }
  F8 v = load8(in, idx * 8, f);
  ushort4* o = (ushort4*)(out + idx * 8);
  o[0] = pack4(v.v[0], v.v[1], v.v[2], v.v[3]);
  o[1] = pack4(v.v[4], v.v[5], v.v[6], v.v[7]);
}

// ---------------------------------------------------------------------------
// gemm_wide (round-2 version, best measured: mode-0 ~82 us, verified).
// BM=256 x BN=128 x BK=64, 512 thr / 8 waves (4M x 2N), per-wave 64x64.
// TWO phases per K-tile, 16 MFMA per phase; full 2-tile prefetch into
// buf[g&1]; checkpoint vmcnt(6); verified 0-conflict swizzle; bijective XCD
// swizzle (grids %8==0).  GEMM interior frozen (rounds 0/2/5 invariant).
// ---------------------------------------------------------------------------
__global__ __launch_bounds__(512, 2) void gemm_wide(
    const unsigned short* __restrict__ A, const unsigned short* __restrict__ B,
    int M, int N, int K, int mode,
    bf16* __restrict__ oq, bf16* __restrict__ ou, float* __restrict__ oc)
{
  __shared__ unsigned short lds[2][384 * 64];   // [buf][(256 A-rows + 128 B-rows) * BK]
  const int tid = threadIdx.x;
  const int wave = tid >> 6, lane = tid & 63;
  const int quad = lane >> 4, l16 = lane & 15;
  const int wm = wave >> 1, wn = wave & 1;      // wave grid 4M x 2N
  const int nbx = N >> 7;                       // BN=128
  const int nwg = gridDim.x;
  const int chunk = nwg >> 3;
  const int swz = (blockIdx.x & 7) * chunk + (blockIdx.x >> 3);
  const int bm = (swz / nbx) * 256, bn = (swz % nbx) * 128;

  // ---- staging lane geometry (inverse-swizzled global source) ----
  const int lrow = lane >> 3;                   // 0..7 rows within an 8-row issue
  const int lslot = (lane & 7) ^ lrow;          // pre-swizzled 16B slot
  const unsigned short* Abase = A + (size_t)(bm + wave * 8 + lrow) * K + lslot * 8;
  const unsigned short* Bbase = B + (size_t)(bn + wave * 8 + lrow) * K + lslot * 8;

  // ---- ds_read geometry (swizzled) ----
  const int x7 = l16 & 7;
  const int s0 = ((0 + quad) ^ x7) * 8;         // kstep 0 slot offset (shorts)
  const int s1 = ((4 + quad) ^ x7) * 8;         // kstep 1
  const int arow0 = (wm * 64 + l16) * 64;       // short offset of A frag row
  const int brow0 = (256 + wn * 64 + l16) * 64; // short offset of B frag row

  f32x4 acc[4][4];
#pragma unroll
  for (int i = 0; i < 4; i++)
#pragma unroll
    for (int j = 0; j < 4; j++) acc[i][j] = f32x4{0.f, 0.f, 0.f, 0.f};

  const int NT = K >> 6;                        // 64-wide K tiles (NT >= 3 here)

  // ---- prologue: tile0 -> buf0 (6 groups), tile1 -> buf1 (6 groups) ----
#pragma unroll
  for (int grp = 0; grp < 4; grp++)
    gld_lds16(Abase + (size_t)grp * 64 * K, &lds[0][(grp * 64 + wave * 8) * 64]);
#pragma unroll
  for (int grp = 0; grp < 2; grp++)
    gld_lds16(Bbase + (size_t)grp * 64 * K, &lds[0][(256 + grp * 64 + wave * 8) * 64]);
#pragma unroll
  for (int grp = 0; grp < 4; grp++)
    gld_lds16(Abase + (size_t)grp * 64 * K + 64, &lds[1][(grp * 64 + wave * 8) * 64]);
#pragma unroll
  for (int grp = 0; grp < 2; grp++)
    gld_lds16(Bbase + (size_t)grp * 64 * K + 64, &lds[1][(256 + grp * 64 + wave * 8) * 64]);
  asm volatile("s_waitcnt vmcnt(6)" ::: "memory");   // tile0 landed; tile1 in flight
  __builtin_amdgcn_sched_barrier(0);
  __builtin_amdgcn_s_barrier();

#define MM(m, n) \
  acc[m][n] = __builtin_amdgcn_mfma_f32_16x16x32_bf16(aF[m][0], bF[n][0], acc[m][n], 0, 0, 0); \
  acc[m][n] = __builtin_amdgcn_mfma_f32_16x16x32_bf16(aF[m][1], bF[n][1], acc[m][n], 0, 0, 0);

  for (int g = 0; g < NT; ++g) {
    const unsigned short* L = lds[g & 1];
    unsigned short* Lw = (unsigned short*)L;     // stage target: same buffer (tile g+2)
    const bool stF = (g + 2) < NT;
    const size_t kF = (size_t)(g + 2) * 64;

    bf16x8 aF[4][2], bF[4][2];

    // ---------------- P1: n-half 0 ----------------
#pragma unroll
    for (int m = 0; m < 4; m++) {
      aF[m][0] = *(const bf16x8*)&L[arow0 + m * 1024 + s0];
      aF[m][1] = *(const bf16x8*)&L[arow0 + m * 1024 + s1];
    }
    bF[0][0] = *(const bf16x8*)&L[brow0 +    0 + s0];
    bF[0][1] = *(const bf16x8*)&L[brow0 +    0 + s1];
    bF[1][0] = *(const bf16x8*)&L[brow0 + 1024 + s0];
    bF[1][1] = *(const bf16x8*)&L[brow0 + 1024 + s1];
    __builtin_amdgcn_s_barrier();                // all waves' A+B(n01) reads done
    if (stF) {                                   // stage A(g+2) into dead A-region
#pragma unroll
      for (int grp = 0; grp < 4; grp++)
        gld_lds16(Abase + (size_t)grp * 64 * K + kF, &Lw[(grp * 64 + wave * 8) * 64]);
    }
    __builtin_amdgcn_s_setprio(1);
    MM(0,0); MM(0,1); MM(1,0); MM(1,1);
    MM(2,0); MM(2,1); MM(3,0); MM(3,1);
    __builtin_amdgcn_s_setprio(0);
    __builtin_amdgcn_s_barrier();

    // ---------------- P2: n-half 1 ----------------
    bF[2][0] = *(const bf16x8*)&L[brow0 + 2048 + s0];
    bF[2][1] = *(const bf16x8*)&L[brow0 + 2048 + s1];
    bF[3][0] = *(const bf16x8*)&L[brow0 + 3072 + s0];
    bF[3][1] = *(const bf16x8*)&L[brow0 + 3072 + s1];
    __builtin_amdgcn_s_barrier();                // all waves' B(n23) reads done
    if (stF) {                                   // stage B(g+2) into dead B-region
#pragma unroll
      for (int grp = 0; grp < 2; grp++)
        gld_lds16(Bbase + (size_t)grp * 64 * K + kF, &Lw[(256 + grp * 64 + wave * 8) * 64]);
    }
    __builtin_amdgcn_s_setprio(1);
    MM(0,2); MM(0,3); MM(1,2); MM(1,3);
    MM(2,2); MM(2,3); MM(3,2); MM(3,3);
    __builtin_amdgcn_s_setprio(0);
    if (stF) { asm volatile("s_waitcnt vmcnt(6)" ::: "memory"); }  // drain tile g+1
    else     { asm volatile("s_waitcnt vmcnt(0)" ::: "memory"); }  // tail
    __builtin_amdgcn_sched_barrier(0);
    __builtin_amdgcn_s_barrier();
  }
#undef MM

  // ---- epilogue ----
#pragma unroll
  for (int m = 0; m < 4; m++)
#pragma unroll
    for (int n = 0; n < 4; n++) {
      int gm0 = bm + wm * 64 + m * 16 + quad * 4;
      int gn  = bn + wn * 64 + n * 16 + l16;
#pragma unroll
      for (int r = 0; r < 4; r++) {
        int gm = gm0 + r;
        float v = acc[m][n][r];
        if (mode == 0) {
          if (gn < QDIM) oq[(size_t)gm * QDIM + gn] = __float2bfloat16(v);
          else           ou[(size_t)gm * DKV + (gn - QDIM)] = __float2bfloat16(v);
        } else {
          oc[(size_t)gm * N + gn] = v;
        }
      }
    }
}

// ---------------------------------------------------------------------------
// xdbl via MFMA — K-SPLIT x4 with PRIVATE PARTIAL BUFFERS (no atomics, no
// memset; round-10's atomicAdd epilogue was the suspected regression there).
// blockIdx.y = s picks a 256-wide K-range (8 iterations); partial results
// store to xdp + s*T_SEQ*96.  256 blocks = 1 block/CU (was 64 = 25% fill);
// serial barrier-chain /4.  xd_reduce sums the 4 partials (coalesced).
// ---------------------------------------------------------------------------
__global__ __launch_bounds__(256) void xdbl_mfma(
    const bf16* __restrict__ u, const unsigned short* __restrict__ xpw_bf,
    float* __restrict__ xdp)
{
  __shared__ unsigned short Us[64 * 32];
  __shared__ unsigned short Ws[96 * 32];
  const int tid = threadIdx.x;
  const int wave = tid >> 6, lane = tid & 63;
  const int quad = lane >> 4, l16 = lane & 15;
  const int t0 = blockIdx.x * 64;
  const int kbeg = blockIdx.y * (DKV / KSPLIT);
  const int kend = kbeg + (DKV / KSPLIT);
  float* xo = xdp + (size_t)blockIdx.y * T_SEQ * 96;
  const unsigned short* ub = (const unsigned short*)u;

  f32x4 acc[6];
#pragma unroll
  for (int j = 0; j < 6; j++) acc[j] = f32x4{0.f, 0.f, 0.f, 0.f};

  const int urow = tid >> 2, ucol = (tid & 3) * 8;
  const int wrow0 = tid >> 2, wcol0 = (tid & 3) * 8;
  const int wrow1 = (256 + tid) >> 2;

  uint4 upre = *(const uint4*)(ub + (size_t)(t0 + urow) * DKV + kbeg + ucol);
  uint4 wpre0 = *(const uint4*)(xpw_bf + (size_t)wrow0 * DKV + kbeg + wcol0);
  uint4 wpre1 = (tid < 128) ? *(const uint4*)(xpw_bf + (size_t)wrow1 * DKV + kbeg + wcol0)
                            : uint4{0, 0, 0, 0};

  for (int k0 = kbeg; k0 < kend; k0 += 32) {
    __syncthreads();
    *(uint4*)&Us[urow * 32 + ucol] = upre;
    *(uint4*)&Ws[wrow0 * 32 + wcol0] = wpre0;
    if (tid < 128) *(uint4*)&Ws[wrow1 * 32 + wcol0] = wpre1;
    __syncthreads();

    int kn = (k0 + 32 < kend) ? (k0 + 32) : k0;
    upre  = *(const uint4*)(ub + (size_t)(t0 + urow) * DKV + kn + ucol);
    wpre0 = *(const uint4*)(xpw_bf + (size_t)wrow0 * DKV + kn + wcol0);
    if (tid < 128) wpre1 = *(const uint4*)(xpw_bf + (size_t)wrow1 * DKV + kn + wcol0);

    bf16x8 a = *(const bf16x8*)&Us[(wave * 16 + l16) * 32 + quad * 8];
#pragma unroll
    for (int j = 0; j < 6; j++) {
      bf16x8 b = *(const bf16x8*)&Ws[(j * 16 + l16) * 32 + quad * 8];
      acc[j] = __builtin_amdgcn_mfma_f32_16x16x32_bf16(a, b, acc[j], 0, 0, 0);
    }
  }

#pragma unroll
  for (int j = 0; j < 6; j++)
#pragma unroll
    for (int r = 0; r < 4; r++) {
      int t = t0 + wave * 16 + quad * 4 + r;
      xo[(size_t)t * 96 + j * 16 + l16] = acc[j][r];
    }
}

// Sum the 4 K-split partials into xd.  float4-vectorized, fully coalesced:
// 98304 float4 elements over 384 blocks x 256 threads.
__global__ __launch_bounds__(256) void xd_reduce(
    const float* __restrict__ xdp, float* __restrict__ xd)
{
  const int i = blockIdx.x * 256 + threadIdx.x;         // 0..98303
  const float4* p0 = (const float4*)xdp + i;
  const float4* p1 = p0 + (T_SEQ * 96 / 4);
  const float4* p2 = p1 + (T_SEQ * 96 / 4);
  const float4* p3 = p2 + (T_SEQ * 96 / 4);
  float4 a = *p0, b = *p1, c = *p2, d = *p3;
  float4 r;
  r.x = (a.x + b.x) + (c.x + d.x);
  r.y = (a.y + b.y) + (c.y + d.y);
  r.z = (a.z + b.z) + (c.z + d.z);
  r.w = (a.w + b.w) + (c.w + d.w);
  ((float4*)xd)[i] = r;
}

// ---------------------------------------------------------------------------
// delta via MFMA (unchanged — verified).
// ---------------------------------------------------------------------------
__global__ __launch_bounds__(256) void delta_mfma(
    const float* __restrict__ xd, const unsigned short* __restrict__ dtw_bf,
    const void* __restrict__ dtb, const int* __restrict__ dflag,
    bf16* __restrict__ delta)
{
  __shared__ unsigned short Xs[64 * 72];
  __shared__ unsigned short Ws[128 * 72];
  const int tid = threadIdx.x;
  const int wave = tid >> 6, lane = tid & 63;
  const int quad = lane >> 4, l16 = lane & 15;
  const int t0 = blockIdx.y * 64, d0 = blockIdx.x * 128;

  for (int e = tid; e < 64 * 8; e += 256) {       // Xs: 64 rows x 64 k (fp32->bf16)
    int row = e >> 3, c8 = (e & 7) * 8;
    const float* p = xd + (size_t)(t0 + row) * 96 + c8;
    float4 a = *(const float4*)p, b = *(const float4*)(p + 4);
    *(ushort4*)&Xs[row * 72 + c8]     = pack4(a.x, a.y, a.z, a.w);
    *(ushort4*)&Xs[row * 72 + c8 + 4] = pack4(b.x, b.y, b.z, b.w);
  }
  for (int e = tid; e < 128 * 8; e += 256) {      // Ws: 128 rows x 64 k
    int row = e >> 3, c8 = (e & 7) * 8;
    *(uint4*)&Ws[row * 72 + c8] = *(const uint4*)(dtw_bf + (size_t)(d0 + row) * DTR + c8);
  }
  __syncthreads();

  bf16x8 a0 = *(const bf16x8*)&Xs[(wave * 16 + l16) * 72 + quad * 8];
  bf16x8 a1 = *(const bf16x8*)&Xs[(wave * 16 + l16) * 72 + 32 + quad * 8];

  f32x4 acc[8];
#pragma unroll
  for (int j = 0; j < 8; j++) {
    bf16x8 b0 = *(const bf16x8*)&Ws[(j * 16 + l16) * 72 + quad * 8];
    bf16x8 b1 = *(const bf16x8*)&Ws[(j * 16 + l16) * 72 + 32 + quad * 8];
    acc[j] = __builtin_amdgcn_mfma_f32_16x16x32_bf16(a0, b0, f32x4{0.f, 0.f, 0.f, 0.f}, 0, 0, 0);
    acc[j] = __builtin_amdgcn_mfma_f32_16x16x32_bf16(a1, b1, acc[j], 0, 0, 0);
  }

  const int f = dflag[0];
#pragma unroll
  for (int j = 0; j < 8; j++) {
    int d = d0 + j * 16 + l16;
    float bias = load1(dtb, d, f);
#pragma unroll
    for (int r = 0; r < 4; r++) {
      int t = t0 + wave * 16 + quad * 4 + r;
      float v = acc[j][r] + bias;
      float sp = fmaxf(v, 0.f) + log1pf(expf(-fabsf(v)));   // stable softplus
      delta[(size_t)t * DKV + d] = __float2bfloat16(sp);
    }
  }
}

// ---------------------------------------------------------------------------
// scan kernels (NCHUNK=64 — measured-best config).
// ---------------------------------------------------------------------------
__global__ __launch_bounds__(256) void scan_pass1(
    const bf16* __restrict__ delta, const bf16* __restrict__ u,
    const float* __restrict__ xd, const void* __restrict__ A_log,
    const int* __restrict__ dflag, float* __restrict__ Pb, float* __restrict__ Hl)
{
  const int gid = blockIdx.x * 256 + threadIdx.x;
  const int c = gid >> 14;
  const int r = gid & 16383;
  const int d = r >> 4, n = r & 15;
  const int f = dflag[0];
  const float A = -expf(load1(A_log, d * NST + n, f));
  float p = 1.f, h = 0.f;
  const int t0 = c * CLEN;
  for (int tt = 0; tt < CLEN; tt++) {
    int t = t0 + tt;
    float dl = bf2f(delta[(size_t)t * DKV + d]);
    float uu = bf2f(u[(size_t)t * DKV + d]);
    float bm = xd[(size_t)t * 96 + DTR + n];
    float a = expf(dl * A);
    h = a * h + dl * bm * uu;
    p *= a;
  }
  Pb[gid] = p;
  Hl[gid] = h;
}

// ---------------------------------------------------------------------------
// scan_combine — register-batched serial (round-12, verified neutral-or-
// better vs round-9; coalesced, loads pipelined, same FP order).
// ---------------------------------------------------------------------------
__global__ __launch_bounds__(256) void scan_combine(
    float* __restrict__ Pb, const float* __restrict__ Hl)
{
  const int idx = blockIdx.x * 256 + threadIdx.x;   // 0..16383, coalesced
  float P[NCHUNK], H[NCHUNK];
#pragma unroll
  for (int c = 0; c < NCHUNK; c++) {
    size_t off = (size_t)c * 16384 + idx;
    P[c] = Pb[off];
    H[c] = Hl[off];
  }
  float run = 0.f;
#pragma unroll
  for (int c = 0; c < NCHUNK; c++) {
    float nrun = P[c] * run + H[c];   // same order as original: p*run + hl
    P[c] = run;                       // P[] reused to hold exclusive prefix
    run = nrun;
  }
#pragma unroll
  for (int c = 0; c < NCHUNK; c++)
    Pb[(size_t)c * 16384 + idx] = P[c];
}

// ---------------------------------------------------------------------------
// scan_pass2 — fuses the V-transpose (verified round 9).
// ---------------------------------------------------------------------------
__global__ __launch_bounds__(256) void scan_pass2(
    const bf16* __restrict__ delta, bf16* __restrict__ u,
    const float* __restrict__ xd, const void* __restrict__ A_log,
    const void* __restrict__ Dp, const int* __restrict__ dflag,
    const float* __restrict__ Hin, unsigned short* __restrict__ vt)
{
  __shared__ unsigned short vtile[16][72];      // 16 d x 64 t (+8 pad)
  const int gid = blockIdx.x * 256 + threadIdx.x;
  const int c = gid >> 14;
  const int r = gid & 16383;
  const int d = r >> 4, n = r & 15;
  const int dblk = ((int)(blockIdx.x & 63)) * 16;   // block-uniform d base
  const bool isV = (dblk >= KDIM);                  // uniform branch
  const int f = dflag[0];
  const float A = -expf(load1(A_log, d * NST + n, f));
  const float dpar = load1(Dp, d, f);
  float h = Hin[gid];
  const int t0 = c * CLEN;
  for (int tt = 0; tt < CLEN; tt++) {
    int t = t0 + tt;
    float dl = bf2f(delta[(size_t)t * DKV + d]);
    float uu = bf2f(u[(size_t)t * DKV + d]);
    float bm = xd[(size_t)t * 96 + DTR + n];
    float cm = xd[(size_t)t * 96 + DTR + NST + n];
    float a = expf(dl * A);
    h = a * h + dl * bm * uu;
    float part = h * cm;
    part += __shfl_xor(part, 1);
    part += __shfl_xor(part, 2);
    part += __shfl_xor(part, 4);
    part += __shfl_xor(part, 8);
    if (n == 0) {
      float outv = part + dpar * uu;
      if (isV) vtile[d & 15][tt] = f2b_bits(outv);
      else     u[(size_t)t * DKV + d] = __float2bfloat16(outv);
    }
  }
  if (isV) {
    __syncthreads();
    const int tid = threadIdx.x;
    const int row = tid >> 4, c4 = (tid & 15) * 4;  // 16 rows x 16 thr x 4 shorts
    ushort4 w;
    w.x = vtile[row][c4];     w.y = vtile[row][c4 + 1];
    w.z = vtile[row][c4 + 2]; w.w = vtile[row][c4 + 3];
    *(ushort4*)&vt[(size_t)(dblk - KDIM + row) * T_SEQ + t0 + c4] = w;
  }
}

// ---------------------------------------------------------------------------
// MFMA flash attention — round-0 structure + T5 setprio (verified round 9).
// ---------------------------------------------------------------------------
__global__ __launch_bounds__(256, 4) void attn_mfma(
    const bf16* __restrict__ q, const bf16* __restrict__ kv,
    const unsigned short* __restrict__ vt, bf16* __restrict__ y)
{
  __shared__ unsigned short Ks[32 * 136];
  __shared__ unsigned short Vts[128 * 40];
  __shared__ unsigned short Ps[4][16 * 40];
  const int tid = threadIdx.x;
  const int wave = tid >> 6, lane = tid & 63;
  const int quad = lane >> 4, l16 = lane & 15;
  const int qt = blockIdx.x, h = blockIdx.y, kvh = h >> 2;
  const int t0 = qt * 64;
  const float scale = 0.088388347648318447f;

  bf16x8 af[4];
#pragma unroll
  for (int s = 0; s < 4; s++)
    af[s] = *(const bf16x8*)(q + (size_t)(t0 + wave * 16 + l16) * QDIM
                             + h * DH + s * 32 + quad * 8);

  const int krow = tid >> 4, kc8 = (tid & 15) * 8;
  const int vrow = tid >> 2, vc8 = (tid & 3) * 8;
  const bf16* kgp = kv + (size_t)kvh * DH;
  const unsigned short* vgp = vt + (size_t)(kvh * DH) * T_SEQ;

  float m_r[4], l_p[4];
  f32x4 O[8];
#pragma unroll
  for (int r = 0; r < 4; r++) { m_r[r] = -1e30f; l_p[r] = 0.f; }
#pragma unroll
  for (int dt = 0; dt < 8; dt++) O[dt] = f32x4{0.f, 0.f, 0.f, 0.f};

  const int kb_start = (t0 > WIN - 1) ? ((t0 - (WIN - 1)) >> 5) : 0;
  const int kb_end = (t0 + 63) >> 5;

  uint4 kp0, kp1, vp0, vp1;
  {
    const int kb = kb_start;
    kp0 = *(const uint4*)(kgp + (size_t)(kb * 32 + krow) * DKV + kc8);
    kp1 = *(const uint4*)(kgp + (size_t)(kb * 32 + 16 + krow) * DKV + kc8);
    vp0 = *(const uint4*)(vgp + (size_t)vrow * T_SEQ + kb * 32 + vc8);
    vp1 = *(const uint4*)(vgp + (size_t)(vrow + 64) * T_SEQ + kb * 32 + vc8);
  }

  for (int kb = kb_start; kb <= kb_end; kb++) {
    __syncthreads();
    *(uint4*)&Ks[krow * 136 + kc8]        = kp0;
    *(uint4*)&Ks[(krow + 16) * 136 + kc8] = kp1;
    *(uint4*)&Vts[vrow * 40 + vc8]        = vp0;
    *(uint4*)&Vts[(vrow + 64) * 40 + vc8] = vp1;
    __syncthreads();

    if (kb < kb_end) {
      const int kn = kb + 1;
      kp0 = *(const uint4*)(kgp + (size_t)(kn * 32 + krow) * DKV + kc8);
      kp1 = *(const uint4*)(kgp + (size_t)(kn * 32 + 16 + krow) * DKV + kc8);
      vp0 = *(const uint4*)(vgp + (size_t)vrow * T_SEQ + kn * 32 + vc8);
      vp1 = *(const uint4*)(vgp + (size_t)(vrow + 64) * T_SEQ + kn * 32 + vc8);
    }

    f32x4 S0 = f32x4{0.f, 0.f, 0.f, 0.f}, S1 = f32x4{0.f, 0.f, 0.f, 0.f};
    __builtin_amdgcn_s_setprio(1);
#pragma unroll
    for (int s = 0; s < 4; s++) {
      bf16x8 b0 = *(const bf16x8*)&Ks[(l16) * 136 + s * 32 + quad * 8];
      bf16x8 b1 = *(const bf16x8*)&Ks[(16 + l16) * 136 + s * 32 + quad * 8];
      S0 = __builtin_amdgcn_mfma_f32_16x16x32_bf16(af[s], b0, S0, 0, 0, 0);
      S1 = __builtin_amdgcn_mfma_f32_16x16x32_bf16(af[s], b1, S1, 0, 0, 0);
    }
    __builtin_amdgcn_s_setprio(0);

    const int ka0 = kb * 32 + l16;
    const int ka1 = ka0 + 16;
    const bool full = (kb * 32 >= t0 + 63 - (WIN - 1)) && (kb * 32 + 31 <= t0);

    float v0r[4], v1r[4];
    bool x0r[4], x1r[4];
    bool ok = true;
#pragma unroll
    for (int r = 0; r < 4; r++) {
      int qa = t0 + wave * 16 + quad * 4 + r;
      float v0 = S0[r] * scale, v1 = S1[r] * scale;
      bool x0 = true, x1 = true;
      if (!full) {
        x0 = (ka0 <= qa) && (ka0 > qa - WIN);
        x1 = (ka1 <= qa) && (ka1 > qa - WIN);
        if (!x0) v0 = -1e30f;
        if (!x1) v1 = -1e30f;
      }
      v0r[r] = v0; v1r[r] = v1; x0r[r] = x0; x1r[r] = x1;
      ok = ok && (fmaxf(v0, v1) <= m_r[r] + 8.f);
    }

    if (!__all((int)ok)) {
#pragma unroll
      for (int r = 0; r < 4; r++) {
        float rm = fmaxf(v0r[r], v1r[r]);
        rm = fmaxf(rm, __shfl_xor(rm, 1));
        rm = fmaxf(rm, __shfl_xor(rm, 2));
        rm = fmaxf(rm, __shfl_xor(rm, 4));
        rm = fmaxf(rm, __shfl_xor(rm, 8));
        float mnew = fmaxf(m_r[r], rm);
        float al = __expf(m_r[r] - mnew);
        m_r[r] = mnew;
        l_p[r] *= al;
#pragma unroll
        for (int dt = 0; dt < 8; dt++) O[dt][r] *= al;
      }
    }

#pragma unroll
    for (int r = 0; r < 4; r++) {
      float p0 = x0r[r] ? __expf(v0r[r] - m_r[r]) : 0.f;
      float p1 = x1r[r] ? __expf(v1r[r] - m_r[r]) : 0.f;
      l_p[r] += p0 + p1;
      Ps[wave][(quad * 4 + r) * 40 + l16]      = f2b_bits(p0);
      Ps[wave][(quad * 4 + r) * 40 + 16 + l16] = f2b_bits(p1);
    }

    bf16x8 pa = *(const bf16x8*)&Ps[wave][l16 * 40 + quad * 8];
    __builtin_amdgcn_s_setprio(1);
#pragma unroll
    for (int dt = 0; dt < 8; dt++) {
      bf16x8 b = *(const bf16x8*)&Vts[(dt * 16 + l16) * 40 + quad * 8];
      O[dt] = __builtin_amdgcn_mfma_f32_16x16x32_bf16(pa, b, O[dt], 0, 0, 0);
    }
    __builtin_amdgcn_s_setprio(0);
  }

  float inv[4];
#pragma unroll
  for (int r = 0; r < 4; r++) {
    float l = l_p[r];
    l += __shfl_xor(l, 1);
    l += __shfl_xor(l, 2);
    l += __shfl_xor(l, 4);
    l += __shfl_xor(l, 8);
    inv[r] = 1.f / l;
  }
#pragma unroll
  for (int dt = 0; dt < 8; dt++)
#pragma unroll
    for (int r = 0; r < 4; r++) {
      int row = t0 + wave * 16 + quad * 4 + r;
      y[(size_t)row * QDIM + h * DH + dt * 16 + l16] = __float2bfloat16(O[dt][r] * inv[r]);
    }
}

// ---------------------------------------------------------------------------
extern "C" void kernel_launch(void* const* d_in, const int* in_sizes, int n_in,
                              void* d_out, int out_size, void* d_ws, size_t ws_size,
                              hipStream_t stream)
{
  const void* x      = d_in[0];
  const void* W_attn = d_in[1];
  const void* A_log  = d_in[2];
  const void* xpw    = d_in[3];
  const void* dtw    = d_in[4];
  const void* dtb    = d_in[5];
  const void* Dp     = d_in[6];
  const void* W_o    = d_in[7];

  // Workspace, TOTAL ~69 MiB:
  char* ws = (char*)d_ws;
  int*   dflag = (int*)ws;   ws += 256;
  bf16*  u     = (bf16*)ws;  ws += (size_t)T_SEQ * DKV * 2;        // 8.4 MB, becomes kv in-place
  float* xd    = (float*)ws; ws += (size_t)T_SEQ * 96 * 4;         // 1.6 MB
  char*  yreg  = ws;                                                // y region (16.78 MB)
  bf16*  delta = (bf16*)ws;  ws += (size_t)T_SEQ * DKV * 2;        // 8.4 MB
  ws += (size_t)64 * DKV * NST * 4;                                 // 4.2 MB (y tail)
  ws += (size_t)64 * DKV * NST * 4;                                 // 4.2 MB (y tail)
  unsigned short* x_bf  = (unsigned short*)ws; ws += (size_t)T_SEQ * NEMBD * 2;  // 16.8 MB; Pb/Hl/xdp reuse after gemm0
  unsigned short* wa_bf = (unsigned short*)ws; ws += (size_t)QKVD * NEMBD * 2;   // 12.6 MB
  unsigned short* wo_bf = (unsigned short*)ws; ws += (size_t)NEMBD * QDIM * 2;   //  8.4 MB
  unsigned short* vt    = (unsigned short*)ws; ws += (size_t)KDIM * T_SEQ * 2;   //  4.2 MB
  unsigned short* xpw_bf = (unsigned short*)ws; ws += (size_t)96 * DKV * 2;      //  0.2 MB
  unsigned short* dtw_bf = (unsigned short*)ws; ws += (size_t)DKV * DTR * 2;     //  0.13 MB
  bf16*  y     = (bf16*)yreg;

  // x_bf region (16.8 MB) is dead after gemm0 (stream-ordered); it hosts:
  //   Pb (4.2 MB) + Hl (4.2 MB) + xdp (4 partials x 1.57 MB = 6.3 MB) = 14.7 MB.
  float* Pb  = (float*)x_bf;
  float* Hl  = Pb + (size_t)NCHUNK * DKV * NST;
  float* xdp = Hl + (size_t)NCHUNK * DKV * NST;

  bf16*  q_bf = (bf16*)d_out;   // q parks in d_out until gemm2 overwrites it
  float* out  = (float*)d_out;

  detect_dtype<<<1, 64, 0, stream>>>((const unsigned short*)x, dflag);
  cvt_all<<<(N8_TOT + 255) / 256, 256, 0, stream>>>(
      x, W_attn, W_o, xpw, dtw, dflag, x_bf, wa_bf, wo_bf, xpw_bf, dtw_bf);

  // BM=256 x BN=128: mode-0 grid = 16*24 = 384, mode-1 grid = 16*16 = 256
  // (exactly 1 block/CU). Both %8 == 0 (bijective XCD swizzle).
  gemm_wide<<<(T_SEQ / 256) * (QKVD / 128), 512, 0, stream>>>(
      x_bf, wa_bf, T_SEQ, QKVD, NEMBD, 0, q_bf, u, nullptr);
  xdbl_mfma<<<dim3(T_SEQ / 64, KSPLIT), 256, 0, stream>>>(u, xpw_bf, xdp);
  xd_reduce<<<T_SEQ * 96 / 4 / 256, 256, 0, stream>>>(xdp, xd);
  delta_mfma<<<dim3(DKV / 128, T_SEQ / 64), 256, 0, stream>>>(xd, dtw_bf, dtb, dflag, delta);
  scan_pass1<<<NCHUNK * 64, 256, 0, stream>>>(delta, u, xd, A_log, dflag, Pb, Hl);
  scan_combine<<<64, 256, 0, stream>>>(Pb, Hl);
  scan_pass2<<<NCHUNK * 64, 256, 0, stream>>>(delta, u, xd, A_log, Dp, dflag, Pb, vt);
  attn_mfma<<<dim3(T_SEQ / 64, NH), 256, 0, stream>>>(q_bf, u, vt, y);
  gemm_wide<<<(T_SEQ / 256) * (QDIM / 128), 512, 0, stream>>>(
      (const unsigned short*)y, wo_bf, T_SEQ, QDIM, QDIM, 1, nullptr, nullptr, out);
}